// Round 1
// baseline (3429.189 us; speedup 1.0000x reference)
//
#include <hip/hip_runtime.h>
#include <stdint.h>
#include <stddef.h>

#define D 256
#define NHEAD 8
#define DHEAD 32

// ---------------- CSR build ----------------
__global__ void hist_edges_k(const int* __restrict__ src, const int* __restrict__ dst,
                             int* cnt_src, int* cnt_dst, int E){
  int e = blockIdx.x*blockDim.x + threadIdx.x;
  if(e < E){ atomicAdd(&cnt_dst[dst[e]],1); atomicAdd(&cnt_src[src[e]],1); }
}
__global__ void hist_batch_k(const int* __restrict__ batch, int* cnt_b, int N){
  int i = blockIdx.x*blockDim.x + threadIdx.x;
  if(i < N) atomicAdd(&cnt_b[batch[i]],1);
}
__global__ void scan_pass1(const int* __restrict__ cnt, int* offs, int* bsums, int n){
  __shared__ int tmp[256];
  int g = blockIdx.x, t = threadIdx.x, i = g*256 + t;
  int v = (i < n) ? cnt[i] : 0;
  tmp[t] = v; __syncthreads();
  for(int off=1; off<256; off<<=1){
    int a = (t>=off) ? tmp[t-off] : 0; __syncthreads();
    tmp[t] += a; __syncthreads();
  }
  if(i < n) offs[i+1] = tmp[t];
  if(t == 255) bsums[g] = tmp[255];
}
__global__ void scan_pass2(int* bsums, int nb){
  __shared__ int tmp[1024];
  int t = threadIdx.x;
  int v = (t < nb) ? bsums[t] : 0;
  tmp[t] = v; __syncthreads();
  for(int off=1; off<1024; off<<=1){
    int a = (t>=off) ? tmp[t-off] : 0; __syncthreads();
    tmp[t] += a; __syncthreads();
  }
  if(t < nb) bsums[t] = tmp[t] - v;   // exclusive
}
__global__ void scan_pass3(int* offs, const int* bsums, int n){
  int i = blockIdx.x*blockDim.x + threadIdx.x;
  if(i == 0) offs[0] = 0;
  if(i < n) offs[i+1] += bsums[i>>8];
}
__global__ void fill_csr_k(const int* __restrict__ seg, const int* __restrict__ other,
                           const int* __restrict__ offs, int* fill, int* sorted, int E){
  int e = blockIdx.x*blockDim.x + threadIdx.x;
  if(e < E){
    int s = seg[e];
    int p = offs[s] + atomicAdd(&fill[s],1);
    sorted[p] = other ? other[e] : e;
  }
}

// ---------------- params prep: Wk_att = Wk @ att (per head) ----------------
__global__ void prep_watt_k(const float* __restrict__ Wk, const float* __restrict__ bk,
                            const float* __restrict__ att, float* __restrict__ wattT,
                            float* __restrict__ batt){
  int tid = blockIdx.x*blockDim.x + threadIdx.x;
  if(tid < 4*NHEAD*D){
    int c = tid & (D-1); int h = (tid>>8) & 7; int p = tid >> 11;
    const float* Wp = Wk + (size_t)p*D*D + (size_t)c*D + h*DHEAD;
    const float* ap = att + (size_t)p*D + h*DHEAD;
    float s = 0.f;
    #pragma unroll
    for(int d=0; d<DHEAD; d++) s += Wp[d]*ap[d];
    wattT[tid] = s;                       // [p][h][c]
  }
  if(tid < 4*NHEAD){
    int h = tid & 7, p = tid >> 3;
    const float* bp = bk + (size_t)p*D + h*DHEAD;
    const float* ap = att + (size_t)p*D + h*DHEAD;
    float s = 0.f;
    #pragma unroll
    for(int d=0; d<DHEAD; d++) s += bp[d]*ap[d];
    batt[tid] = s;
  }
}

// alpha[n,h] = x[n,:] . wattT[h,:] + batt[h]
__global__ void alpha_k(const float* __restrict__ X, const float* __restrict__ wattT,
                        const float* __restrict__ batt, float* __restrict__ alpha, int n){
  int tid = blockIdx.x*blockDim.x + threadIdx.x;
  if(tid >= n*NHEAD) return;
  int h = tid & 7, row = tid >> 3;
  const float4* x4 = (const float4*)(X + (size_t)row*D);
  const float4* w4 = (const float4*)(wattT + (size_t)h*D);
  float s = batt[h];
  #pragma unroll 8
  for(int c=0; c<D/4; c++){
    float4 a = x4[c], b = w4[c];
    s += a.x*b.x + a.y*b.y + a.z*b.z + a.w*b.w;
  }
  alpha[tid] = s;
}

// ---------------- fp32 tiled GEMM: C[n,256] = A[n,256] @ W[256,256] + bias ----------------
template<bool RELU>
__global__ __launch_bounds__(256) void gemm256(const float* __restrict__ A, const float* __restrict__ W,
                                               const float* __restrict__ bias, float* __restrict__ C, int n){
  __shared__ float As[16][68];
  __shared__ float Bs[16][68];
  const int tid = threadIdx.x;
  const int tx = tid & 15, ty = tid >> 4;
  const int row0 = blockIdx.x*64, col0 = blockIdx.y*64;
  float acc[4][4] = {};
  const int mA = tid >> 2, k4 = (tid & 3) << 2;
  const int kb = tid >> 4, n4 = (tid & 15) << 2;
  for(int k0=0; k0<D; k0+=16){
    float4 av = make_float4(0.f,0.f,0.f,0.f);
    if(row0 + mA < n) av = *(const float4*)&A[(size_t)(row0+mA)*D + k0 + k4];
    float4 bv = *(const float4*)&W[(size_t)(k0+kb)*D + col0 + n4];
    As[k4+0][mA]=av.x; As[k4+1][mA]=av.y; As[k4+2][mA]=av.z; As[k4+3][mA]=av.w;
    *(float4*)&Bs[kb][n4] = bv;
    __syncthreads();
    #pragma unroll
    for(int k=0; k<16; k++){
      float4 a4 = *(const float4*)&As[k][ty<<2];
      float4 b4 = *(const float4*)&Bs[k][tx<<2];
      acc[0][0]+=a4.x*b4.x; acc[0][1]+=a4.x*b4.y; acc[0][2]+=a4.x*b4.z; acc[0][3]+=a4.x*b4.w;
      acc[1][0]+=a4.y*b4.x; acc[1][1]+=a4.y*b4.y; acc[1][2]+=a4.y*b4.z; acc[1][3]+=a4.y*b4.w;
      acc[2][0]+=a4.z*b4.x; acc[2][1]+=a4.z*b4.y; acc[2][2]+=a4.z*b4.z; acc[2][3]+=a4.z*b4.w;
      acc[3][0]+=a4.w*b4.x; acc[3][1]+=a4.w*b4.y; acc[3][2]+=a4.w*b4.z; acc[3][3]+=a4.w*b4.w;
    }
    __syncthreads();
  }
  #pragma unroll
  for(int i=0; i<4; i++){
    int r = row0 + (ty<<2) + i;
    if(r >= n) continue;
    #pragma unroll
    for(int j=0; j<4; j++){
      float v = acc[i][j] + bias[col0 + (tx<<2) + j];
      if(RELU) v = fmaxf(v, 0.f);
      C[(size_t)r*D + col0 + (tx<<2) + j] = v;
    }
  }
}

// ---------------- block reductions ----------------
__device__ __forceinline__ float block_sum256(float v, float* red){
  #pragma unroll
  for(int m=32; m; m>>=1) v += __shfl_xor(v, m);
  if((threadIdx.x & 63) == 0) red[threadIdx.x >> 6] = v;
  __syncthreads();
  float s = red[0] + red[1] + red[2] + red[3];
  __syncthreads();
  return s;
}

// ---------------- PMA pool: segment softmax + weighted V sum + seed residual + LN0 ----------------
__global__ __launch_bounds__(256) void pma_pool(const float* __restrict__ V, const float* __restrict__ alpha,
    const int* __restrict__ offs, const int* __restrict__ glist,
    const float* __restrict__ attp, const float* __restrict__ g0, const float* __restrict__ b0,
    float* __restrict__ U, int nseg){
  __shared__ float red[4];
  int s = blockIdx.x;
  int t = threadIdx.x;
  int h = t >> 5;
  int e0 = offs[s], e1 = offs[s+1];
  float m = -3.0e38f;
  for(int e=e0; e<e1; e++){
    float a = alpha[glist[e]*NHEAD + h];
    a = (a > 0.f) ? a : 0.2f*a;
    m = fmaxf(m, a);
  }
  float wsum = 0.f, acc = 0.f;
  for(int e=e0; e<e1; e++){
    int g = glist[e];
    float a = alpha[g*NHEAD + h];
    a = (a > 0.f) ? a : 0.2f*a;
    float w = __expf(a - m);
    wsum += w;
    acc += w * V[(size_t)g*D + t];
  }
  float out = acc / ((wsum > 0.f) ? wsum : 1.f) + attp[t];
  float mu  = block_sum256(out, red) * (1.f/D);
  float dd  = out - mu;
  float var = block_sum256(dd*dd, red) * (1.f/D);
  U[(size_t)s*D + t] = dd * rsqrtf(var + 1e-5f) * g0[t] + b0[t];
}

// ---------------- rFF tail: X = relu(LN1(U + relu(R)))  (in-place over U) ----------------
__global__ __launch_bounds__(256) void rff_tail(const float* __restrict__ R, float* __restrict__ U,
    const float* __restrict__ g1, const float* __restrict__ b1p, int nseg){
  __shared__ float red[4];
  int s = blockIdx.x, t = threadIdx.x;
  float v = U[(size_t)s*D + t] + fmaxf(R[(size_t)s*D + t], 0.f);
  float mu  = block_sum256(v, red) * (1.f/D);
  float dd  = v - mu;
  float var = block_sum256(dd*dd, red) * (1.f/D);
  float y = dd * rsqrtf(var + 1e-5f) * g1[t] + b1p[t];
  U[(size_t)s*D + t] = fmaxf(y, 0.f);
}

// ---------------- readout: segment mean per batch ----------------
__global__ __launch_bounds__(256) void readout_k(const float* __restrict__ X, const int* __restrict__ offsb,
    const int* __restrict__ nidx, float* __restrict__ ro){
  int b = blockIdx.x, t = threadIdx.x;
  int e0 = offsb[b], e1 = offsb[b+1];
  float s = 0.f;
  for(int i=e0; i<e1; i++) s += X[(size_t)nidx[i]*D + t];
  int c = e1 - e0;
  ro[b*D + t] = s / ((c > 0) ? (float)c : 1.f);
}

// ---------------- classifier: LN(ro@cW1+cb1) relu @ cW2 + cb2 ----------------
__global__ __launch_bounds__(128) void classifier_k(const float* __restrict__ ro, const float* __restrict__ cW1,
    const float* __restrict__ cb1, const float* __restrict__ clng, const float* __restrict__ clnb,
    const float* __restrict__ cW2, const float* __restrict__ cb2, float* __restrict__ out){
  __shared__ float xs[256];
  __shared__ float hs[128];
  __shared__ float red[2];
  int b = blockIdx.x, j = threadIdx.x;
  xs[j] = ro[b*256 + j]; xs[j+128] = ro[b*256 + j + 128];
  __syncthreads();
  float hv = cb1[j];
  for(int c=0; c<256; c++) hv += xs[c]*cW1[c*128 + j];
  float v = hv;
  #pragma unroll
  for(int mm=32; mm; mm>>=1) v += __shfl_xor(v, mm);
  if((j & 63) == 0) red[j>>6] = v;
  __syncthreads();
  float mu = (red[0] + red[1]) * (1.f/128.f);
  __syncthreads();
  float dd = hv - mu;
  v = dd*dd;
  #pragma unroll
  for(int mm=32; mm; mm>>=1) v += __shfl_xor(v, mm);
  if((j & 63) == 0) red[j>>6] = v;
  __syncthreads();
  float var = (red[0] + red[1]) * (1.f/128.f);
  float hn = fmaxf(dd * rsqrtf(var + 1e-5f) * clng[j] + clnb[j], 0.f);
  hs[j] = hn;
  __syncthreads();
  if(j < 10){
    float o = cb2[j];
    #pragma unroll
    for(int c=0; c<128; c++) o += hs[c]*cW2[c*10 + j];
    out[b*10 + j] = o;
  }
}

extern "C" void kernel_launch(void* const* d_in, const int* in_sizes, int n_in,
                              void* d_out, int out_size, void* d_ws, size_t ws_size,
                              hipStream_t stream){
  const float* X0   = (const float*)d_in[0];
  const int*   src  = (const int*)d_in[1];
  const int*   dst  = (const int*)d_in[2];
  const int*   batch= (const int*)d_in[3];
  const float* Wk   = (const float*)d_in[6];
  const float* bk   = (const float*)d_in[7];
  const float* Wv   = (const float*)d_in[8];
  const float* bv   = (const float*)d_in[9];
  const float* att  = (const float*)d_in[10];
  const float* ln0g = (const float*)d_in[11];
  const float* ln0b = (const float*)d_in[12];
  const float* ln1g = (const float*)d_in[13];
  const float* ln1b = (const float*)d_in[14];
  const float* W1   = (const float*)d_in[15];
  const float* b1   = (const float*)d_in[16];
  const float* W2   = (const float*)d_in[17];
  const float* b2   = (const float*)d_in[18];
  const float* cW1  = (const float*)d_in[19];
  const float* cb1  = (const float*)d_in[20];
  const float* clng = (const float*)d_in[21];
  const float* clnb = (const float*)d_in[22];
  const float* cW2  = (const float*)d_in[23];
  const float* cb2  = (const float*)d_in[24];

  const int N = in_sizes[0] / D;     // 100000
  const int E = in_sizes[1];         // 400000
  const int M = 20000, B = 64;

  char* p = (char*)d_ws;
  auto carve = [&](size_t bytes)->void*{
    void* r = (void*)p; p += (bytes + 255) & ~(size_t)255; return r;
  };
  float* bufA   = (float*)carve((size_t)N*D*4);
  float* bufV   = (float*)carve((size_t)N*D*4);
  float* bufT   = (float*)carve((size_t)N*D*4);
  float* alphaB = (float*)carve((size_t)N*NHEAD*4);
  float* wattT  = (float*)carve(4*NHEAD*D*4);
  float* batt   = (float*)carve(4*NHEAD*4);
  float* ro     = (float*)carve((size_t)B*D*4);
  int* offs_dst = (int*)carve((size_t)(M+1)*4);
  int* offs_src = (int*)carve((size_t)(N+1)*4);
  int* offs_b   = (int*)carve((size_t)(B+1)*4);
  int* sorted_dst = (int*)carve((size_t)E*4);
  int* sorted_src = (int*)carve((size_t)E*4);
  int* sorted_b   = (int*)carve((size_t)N*4);
  int* bsums    = (int*)carve(1024*4);
  char* z0 = p;                       // contiguous zero-init block
  int* cnt_dst = (int*)carve((size_t)M*4);
  int* cnt_src = (int*)carve((size_t)N*4);
  int* cnt_b   = (int*)carve((size_t)B*4);
  int* fill_dst= (int*)carve((size_t)M*4);
  int* fill_src= (int*)carve((size_t)N*4);
  int* fill_b  = (int*)carve((size_t)B*4);
  size_t zbytes = (size_t)(p - z0);
  hipMemsetAsync(z0, 0, zbytes, stream);

  // CSR builds
  hist_edges_k<<<(E+255)/256,256,0,stream>>>(src, dst, cnt_src, cnt_dst, E);
  hist_batch_k<<<(N+255)/256,256,0,stream>>>(batch, cnt_b, N);
  auto scan = [&](const int* cnt, int* offs, int n){
    int nb = (n+255)/256;
    scan_pass1<<<nb,256,0,stream>>>(cnt, offs, bsums, n);
    scan_pass2<<<1,1024,0,stream>>>(bsums, nb);
    scan_pass3<<<(n+255)/256,256,0,stream>>>(offs, bsums, n);
  };
  scan(cnt_dst, offs_dst, M);
  fill_csr_k<<<(E+255)/256,256,0,stream>>>(dst, src, offs_dst, fill_dst, sorted_dst, E);
  scan(cnt_src, offs_src, N);
  fill_csr_k<<<(E+255)/256,256,0,stream>>>(src, dst, offs_src, fill_src, sorted_src, E);
  scan(cnt_b, offs_b, B);
  fill_csr_k<<<(N+255)/256,256,0,stream>>>(batch, nullptr, offs_b, fill_b, sorted_b, N);

  prep_watt_k<<<(4*NHEAD*D+255)/256,256,0,stream>>>(Wk, bk, att, wattT, batt);

  const float* xin = X0;
  for(int pi=0; pi<4; pi++){
    int n_rows = (pi & 1) ? M : N;       // rows of PMA input
    int nseg   = (pi & 1) ? N : M;       // pooled output rows
    const int* offs = (pi & 1) ? offs_src : offs_dst;
    const int* gl   = (pi & 1) ? sorted_src : sorted_dst;

    alpha_k<<<((size_t)n_rows*NHEAD+255)/256,256,0,stream>>>(
        xin, wattT + pi*NHEAD*D, batt + pi*NHEAD, alphaB, n_rows);
    dim3 gv((n_rows+63)/64, 4);
    gemm256<false><<<gv,256,0,stream>>>(xin, Wv + (size_t)pi*D*D, bv + pi*D, bufV, n_rows);
    pma_pool<<<nseg,256,0,stream>>>(bufV, alphaB, offs, gl,
        att + pi*D, ln0g + pi*D, ln0b + pi*D, bufA, nseg);
    dim3 gt((nseg+63)/64, 4);
    gemm256<true ><<<gt,256,0,stream>>>(bufA, W1 + (size_t)pi*D*D, b1 + pi*D, bufT, nseg);
    gemm256<false><<<gt,256,0,stream>>>(bufT, W2 + (size_t)pi*D*D, b2 + pi*D, bufV, nseg);
    rff_tail<<<nseg,256,0,stream>>>(bufV, bufA, ln1g + pi*D, ln1b + pi*D, nseg);
    xin = bufA;
  }

  readout_k<<<B,256,0,stream>>>(bufA, offs_b, sorted_b, ro);
  classifier_k<<<B,128,0,stream>>>(ro, cW1, cb1, clng, clnb, cW2, cb2, (float*)d_out);
}

// Round 2
// 2123.973 us; speedup vs baseline: 1.6145x; 1.6145x over previous
//
#include <hip/hip_runtime.h>
#include <stdint.h>
#include <stddef.h>

#define D 256
#define NHEAD 8
#define DHEAD 32

typedef short bf16x8 __attribute__((ext_vector_type(8)));
typedef float f32x4  __attribute__((ext_vector_type(4)));

__device__ __forceinline__ unsigned short f2b(float f){
  uint32_t u = __float_as_uint(f);
  u += 0x7FFF + ((u >> 16) & 1);
  return (unsigned short)(u >> 16);
}
__device__ __forceinline__ float b2f(unsigned short b){
  return __uint_as_float(((uint32_t)b) << 16);
}

// ---------------- CSR build ----------------
__global__ void hist_edges_k(const int* __restrict__ src, const int* __restrict__ dst,
                             int* cnt_src, int* cnt_dst, int E){
  int e = blockIdx.x*blockDim.x + threadIdx.x;
  if(e < E){ atomicAdd(&cnt_dst[dst[e]],1); atomicAdd(&cnt_src[src[e]],1); }
}
__global__ void hist_batch_k(const int* __restrict__ batch, int* cnt_b, int N){
  int i = blockIdx.x*blockDim.x + threadIdx.x;
  if(i < N) atomicAdd(&cnt_b[batch[i]],1);
}
__global__ void scan_pass1(const int* __restrict__ cnt, int* offs, int* bsums, int n){
  __shared__ int tmp[256];
  int g = blockIdx.x, t = threadIdx.x, i = g*256 + t;
  int v = (i < n) ? cnt[i] : 0;
  tmp[t] = v; __syncthreads();
  for(int off=1; off<256; off<<=1){
    int a = (t>=off) ? tmp[t-off] : 0; __syncthreads();
    tmp[t] += a; __syncthreads();
  }
  if(i < n) offs[i+1] = tmp[t];
  if(t == 255) bsums[g] = tmp[255];
}
__global__ void scan_pass2(int* bsums, int nb){
  __shared__ int tmp[1024];
  int t = threadIdx.x;
  int v = (t < nb) ? bsums[t] : 0;
  tmp[t] = v; __syncthreads();
  for(int off=1; off<1024; off<<=1){
    int a = (t>=off) ? tmp[t-off] : 0; __syncthreads();
    tmp[t] += a; __syncthreads();
  }
  if(t < nb) bsums[t] = tmp[t] - v;   // exclusive
}
__global__ void scan_pass3(int* offs, const int* bsums, int n){
  int i = blockIdx.x*blockDim.x + threadIdx.x;
  if(i == 0) offs[0] = 0;
  if(i < n) offs[i+1] += bsums[i>>8];
}
__global__ void fill_csr_k(const int* __restrict__ seg, const int* __restrict__ other,
                           const int* __restrict__ offs, int* fill, int* sorted, int E){
  int e = blockIdx.x*blockDim.x + threadIdx.x;
  if(e < E){
    int s = seg[e];
    int p = offs[s] + atomicAdd(&fill[s],1);
    sorted[p] = other ? other[e] : e;
  }
}

// ---------------- conversions ----------------
__global__ void conv_x_k(const float* __restrict__ X, unsigned short* __restrict__ Xb, int total8){
  int i = blockIdx.x*blockDim.x + threadIdx.x;
  if(i >= total8) return;
  float4 a = ((const float4*)X)[2*i], b = ((const float4*)X)[2*i+1];
  union { unsigned short u[8]; uint4 v; } o;
  o.u[0]=f2b(a.x); o.u[1]=f2b(a.y); o.u[2]=f2b(a.z); o.u[3]=f2b(a.w);
  o.u[4]=f2b(b.x); o.u[5]=f2b(b.y); o.u[6]=f2b(b.z); o.u[7]=f2b(b.w);
  ((uint4*)Xb)[i] = o.v;
}

// WtAll[set][p][n][k] = Wset[p][k][n], bf16.  set: 0=Wv, 1=W1, 2=W2
__global__ void conv_wt_k(const float* __restrict__ Wv, const float* __restrict__ W1,
                          const float* __restrict__ W2, unsigned short* __restrict__ Wt){
  int tid = blockIdx.x*blockDim.x + threadIdx.x;
  if(tid >= 3*4*256*256) return;
  int k = tid & 255, nn = (tid>>8)&255, p = (tid>>16)&3, s = tid>>18;
  const float* W = (s==0)?Wv:((s==1)?W1:W2);
  Wt[tid] = f2b(W[(size_t)p*65536 + (size_t)k*256 + nn]);
}

// ---------------- params prep: Wk_att = Wk @ att (per head), fp32 ----------------
__global__ void prep_watt_k(const float* __restrict__ Wk, const float* __restrict__ bk,
                            const float* __restrict__ att, float* __restrict__ wattT,
                            float* __restrict__ batt){
  int tid = blockIdx.x*blockDim.x + threadIdx.x;
  if(tid < 4*NHEAD*D){
    int c = tid & (D-1); int h = (tid>>8) & 7; int p = tid >> 11;
    const float* Wp = Wk + (size_t)p*D*D + (size_t)c*D + h*DHEAD;
    const float* ap = att + (size_t)p*D + h*DHEAD;
    float s = 0.f;
    #pragma unroll
    for(int d=0; d<DHEAD; d++) s += Wp[d]*ap[d];
    wattT[tid] = s;                       // [p][h][c]
  }
  if(tid < 4*NHEAD){
    int h = tid & 7, p = tid >> 3;
    const float* bp = bk + (size_t)p*D + h*DHEAD;
    const float* ap = att + (size_t)p*D + h*DHEAD;
    float s = 0.f;
    #pragma unroll
    for(int d=0; d<DHEAD; d++) s += bp[d]*ap[d];
    batt[tid] = s;
  }
}

// alpha[n,h] = x[n,:] . wattT[h,:] + batt[h]   (x bf16, watt fp32)
__global__ void alpha_k(const unsigned short* __restrict__ X, const float* __restrict__ wattT,
                        const float* __restrict__ batt, float* __restrict__ alpha, int n){
  int tid = blockIdx.x*blockDim.x + threadIdx.x;
  if(tid >= n*NHEAD) return;
  int h = tid & 7, row = tid >> 3;
  const uint4* x4 = (const uint4*)(X + (size_t)row*D);
  const float* wp = wattT + (size_t)h*D;
  float s = batt[h];
  #pragma unroll 4
  for(int c=0; c<32; c++){
    uint4 xv = x4[c];
    const float* w = wp + c*8;
    s += b2f((unsigned short)(xv.x&0xffff))*w[0] + b2f((unsigned short)(xv.x>>16))*w[1]
       + b2f((unsigned short)(xv.y&0xffff))*w[2] + b2f((unsigned short)(xv.y>>16))*w[3]
       + b2f((unsigned short)(xv.z&0xffff))*w[4] + b2f((unsigned short)(xv.z>>16))*w[5]
       + b2f((unsigned short)(xv.w&0xffff))*w[6] + b2f((unsigned short)(xv.w>>16))*w[7];
  }
  alpha[tid] = s;
}

// ---------------- bf16 MFMA GEMM: C[n,256] = A[n,256] @ W[256,256] + bias ----------------
// A row-major bf16; Wt[n][k] = W[k][n] bf16 (transposed); C bf16; bias fp32.
// 256 thr = 4 waves (2x2 of 64x64), tile 128x128, grid (ceil(n/128), 2). No LDS.
template<bool RELU>
__global__ __launch_bounds__(256) void gemm_mfma(const unsigned short* __restrict__ A,
    const unsigned short* __restrict__ Wt, const float* __restrict__ bias,
    unsigned short* __restrict__ C, int n){
  const int w = threadIdx.x >> 6, l = threadIdx.x & 63;
  const int wr = w >> 1, wc = w & 1;
  const int row0 = blockIdx.x*128 + wr*64;
  const int col0 = blockIdx.y*128 + wc*64;
  const int lr = l & 15, lg = l >> 4;
  f32x4 acc[4][4] = {};
  #pragma unroll
  for(int k0=0; k0<256; k0+=32){
    bf16x8 af[4], bf_[4];
    #pragma unroll
    for(int mi=0; mi<4; mi++){
      int r = row0 + mi*16 + lr;
      r = (r < n) ? r : (n-1);
      af[mi] = *(const bf16x8*)(A + (size_t)r*256 + k0 + lg*8);
    }
    #pragma unroll
    for(int ni=0; ni<4; ni++){
      int c = col0 + ni*16 + lr;
      bf_[ni] = *(const bf16x8*)(Wt + (size_t)c*256 + k0 + lg*8);
    }
    #pragma unroll
    for(int mi=0; mi<4; mi++)
      #pragma unroll
      for(int ni=0; ni<4; ni++)
        acc[mi][ni] = __builtin_amdgcn_mfma_f32_16x16x32_bf16(af[mi], bf_[ni], acc[mi][ni], 0, 0, 0);
  }
  #pragma unroll
  for(int mi=0; mi<4; mi++){
    #pragma unroll
    for(int r4=0; r4<4; r4++){
      int row = row0 + mi*16 + lg*4 + r4;
      if(row >= n) continue;
      #pragma unroll
      for(int ni=0; ni<4; ni++){
        int col = col0 + ni*16 + lr;
        float v = acc[mi][ni][r4] + bias[col];
        if(RELU) v = fmaxf(v, 0.f);
        C[(size_t)row*256 + col] = f2b(v);
      }
    }
  }
}

// ---------------- block reductions ----------------
__device__ __forceinline__ float block_sum256(float v, float* red){
  #pragma unroll
  for(int m=32; m; m>>=1) v += __shfl_xor(v, m);
  if((threadIdx.x & 63) == 0) red[threadIdx.x >> 6] = v;
  __syncthreads();
  float s = red[0] + red[1] + red[2] + red[3];
  __syncthreads();
  return s;
}

// ---------------- PMA pool: segment softmax + weighted V sum + seed residual + LN0 ----------------
__global__ __launch_bounds__(256) void pma_pool(const unsigned short* __restrict__ V,
    const float* __restrict__ alpha,
    const int* __restrict__ offs, const int* __restrict__ glist,
    const float* __restrict__ attp, const float* __restrict__ g0, const float* __restrict__ b0,
    unsigned short* __restrict__ U, int nseg){
  __shared__ float red[4];
  int s = blockIdx.x;
  int t = threadIdx.x;
  int h = t >> 5;
  int e0 = offs[s], e1 = offs[s+1];
  float m = -3.0e38f;
  for(int e=e0; e<e1; e++){
    float a = alpha[glist[e]*NHEAD + h];
    a = (a > 0.f) ? a : 0.2f*a;
    m = fmaxf(m, a);
  }
  float wsum = 0.f, acc = 0.f;
  for(int e=e0; e<e1; e++){
    int g = glist[e];
    float a = alpha[g*NHEAD + h];
    a = (a > 0.f) ? a : 0.2f*a;
    float w = __expf(a - m);
    wsum += w;
    acc += w * b2f(V[(size_t)g*D + t]);
  }
  float out = acc / ((wsum > 0.f) ? wsum : 1.f) + attp[t];
  float mu  = block_sum256(out, red) * (1.f/D);
  float dd  = out - mu;
  float var = block_sum256(dd*dd, red) * (1.f/D);
  U[(size_t)s*D + t] = f2b(dd * rsqrtf(var + 1e-5f) * g0[t] + b0[t]);
}

// ---------------- rFF tail: X = relu(LN1(U + relu(R)))  (in-place over U) ----------------
__global__ __launch_bounds__(256) void rff_tail(const unsigned short* __restrict__ R,
    unsigned short* __restrict__ U,
    const float* __restrict__ g1, const float* __restrict__ b1p, int nseg){
  __shared__ float red[4];
  int s = blockIdx.x, t = threadIdx.x;
  float v = b2f(U[(size_t)s*D + t]) + fmaxf(b2f(R[(size_t)s*D + t]), 0.f);
  float mu  = block_sum256(v, red) * (1.f/D);
  float dd  = v - mu;
  float var = block_sum256(dd*dd, red) * (1.f/D);
  float y = dd * rsqrtf(var + 1e-5f) * g1[t] + b1p[t];
  U[(size_t)s*D + t] = f2b(fmaxf(y, 0.f));
}

// ---------------- readout: chunked segment-sum with atomics ----------------
__global__ __launch_bounds__(256) void readout_acc(const unsigned short* __restrict__ X,
    const int* __restrict__ offsb, const int* __restrict__ nidx, float* __restrict__ ro){
  int b = blockIdx.x, chunk = blockIdx.y, t = threadIdx.x;
  int e0 = offsb[b], e1 = offsb[b+1];
  int len = e1 - e0;
  int per = (len + gridDim.y - 1) / gridDim.y;
  int s0 = e0 + chunk*per;
  int s1 = min(s0 + per, e1);
  if(s0 >= s1) return;
  float s = 0.f;
  for(int i=s0; i<s1; i++) s += b2f(X[(size_t)nidx[i]*D + t]);
  atomicAdd(&ro[b*D + t], s);
}

// ---------------- classifier: LN(ro/cnt @ cW1 + cb1) relu @ cW2 + cb2 ----------------
__global__ __launch_bounds__(128) void classifier_k(const float* __restrict__ ro,
    const int* __restrict__ offsb,
    const float* __restrict__ cW1, const float* __restrict__ cb1,
    const float* __restrict__ clng, const float* __restrict__ clnb,
    const float* __restrict__ cW2, const float* __restrict__ cb2, float* __restrict__ out){
  __shared__ float xs[256];
  __shared__ float hs[128];
  __shared__ float red[2];
  int b = blockIdx.x, j = threadIdx.x;
  int cnt = offsb[b+1] - offsb[b];
  float sc = 1.f / ((cnt > 0) ? (float)cnt : 1.f);
  xs[j] = ro[b*256 + j]*sc; xs[j+128] = ro[b*256 + j + 128]*sc;
  __syncthreads();
  float hv = cb1[j];
  for(int c=0; c<256; c++) hv += xs[c]*cW1[c*128 + j];
  float v = hv;
  #pragma unroll
  for(int mm=32; mm; mm>>=1) v += __shfl_xor(v, mm);
  if((j & 63) == 0) red[j>>6] = v;
  __syncthreads();
  float mu = (red[0] + red[1]) * (1.f/128.f);
  __syncthreads();
  float dd = hv - mu;
  v = dd*dd;
  #pragma unroll
  for(int mm=32; mm; mm>>=1) v += __shfl_xor(v, mm);
  if((j & 63) == 0) red[j>>6] = v;
  __syncthreads();
  float var = (red[0] + red[1]) * (1.f/128.f);
  float hn = fmaxf(dd * rsqrtf(var + 1e-5f) * clng[j] + clnb[j], 0.f);
  hs[j] = hn;
  __syncthreads();
  if(j < 10){
    float o = cb2[j];
    #pragma unroll
    for(int c=0; c<128; c++) o += hs[c]*cW2[c*10 + j];
    out[b*10 + j] = o;
  }
}

extern "C" void kernel_launch(void* const* d_in, const int* in_sizes, int n_in,
                              void* d_out, int out_size, void* d_ws, size_t ws_size,
                              hipStream_t stream){
  const float* X0   = (const float*)d_in[0];
  const int*   src  = (const int*)d_in[1];
  const int*   dst  = (const int*)d_in[2];
  const int*   batch= (const int*)d_in[3];
  const float* Wk   = (const float*)d_in[6];
  const float* bk   = (const float*)d_in[7];
  const float* Wv   = (const float*)d_in[8];
  const float* bv   = (const float*)d_in[9];
  const float* att  = (const float*)d_in[10];
  const float* ln0g = (const float*)d_in[11];
  const float* ln0b = (const float*)d_in[12];
  const float* ln1g = (const float*)d_in[13];
  const float* ln1b = (const float*)d_in[14];
  const float* W1   = (const float*)d_in[15];
  const float* b1   = (const float*)d_in[16];
  const float* W2   = (const float*)d_in[17];
  const float* b2   = (const float*)d_in[18];
  const float* cW1  = (const float*)d_in[19];
  const float* cb1  = (const float*)d_in[20];
  const float* clng = (const float*)d_in[21];
  const float* clnb = (const float*)d_in[22];
  const float* cW2  = (const float*)d_in[23];
  const float* cb2  = (const float*)d_in[24];

  const int N = in_sizes[0] / D;     // 100000
  const int E = in_sizes[1];         // 400000
  const int M = 20000, B = 64;

  char* p = (char*)d_ws;
  auto carve = [&](size_t bytes)->void*{
    void* r = (void*)p; p += (bytes + 255) & ~(size_t)255; return r;
  };
  unsigned short* Xb   = (unsigned short*)carve((size_t)N*D*2);
  unsigned short* bufA = (unsigned short*)carve((size_t)N*D*2);
  unsigned short* bufV = (unsigned short*)carve((size_t)N*D*2);
  unsigned short* bufT = (unsigned short*)carve((size_t)N*D*2);
  unsigned short* WtAll= (unsigned short*)carve((size_t)3*4*65536*2);
  float* alphaB = (float*)carve((size_t)N*NHEAD*4);
  float* wattT  = (float*)carve(4*NHEAD*D*4);
  float* batt   = (float*)carve(4*NHEAD*4);
  int* offs_dst = (int*)carve((size_t)(M+1)*4);
  int* offs_src = (int*)carve((size_t)(N+1)*4);
  int* offs_b   = (int*)carve((size_t)(B+1)*4);
  int* sorted_dst = (int*)carve((size_t)E*4);
  int* sorted_src = (int*)carve((size_t)E*4);
  int* sorted_b   = (int*)carve((size_t)N*4);
  int* bsums    = (int*)carve(1024*4);
  char* z0 = p;                       // contiguous zero-init block
  int* cnt_dst = (int*)carve((size_t)M*4);
  int* cnt_src = (int*)carve((size_t)N*4);
  int* cnt_b   = (int*)carve((size_t)B*4);
  int* fill_dst= (int*)carve((size_t)M*4);
  int* fill_src= (int*)carve((size_t)N*4);
  int* fill_b  = (int*)carve((size_t)B*4);
  float* ro    = (float*)carve((size_t)B*D*4);
  size_t zbytes = (size_t)(p - z0);
  hipMemsetAsync(z0, 0, zbytes, stream);

  // conversions
  conv_x_k<<<(N*D/8+255)/256,256,0,stream>>>(X0, Xb, N*D/8);
  conv_wt_k<<<(3*4*65536+255)/256,256,0,stream>>>(Wv, W1, W2, WtAll);
  prep_watt_k<<<(4*NHEAD*D+255)/256,256,0,stream>>>(Wk, bk, att, wattT, batt);

  // CSR builds
  hist_edges_k<<<(E+255)/256,256,0,stream>>>(src, dst, cnt_src, cnt_dst, E);
  hist_batch_k<<<(N+255)/256,256,0,stream>>>(batch, cnt_b, N);
  auto scan = [&](const int* cnt, int* offs, int n){
    int nb = (n+255)/256;
    scan_pass1<<<nb,256,0,stream>>>(cnt, offs, bsums, n);
    scan_pass2<<<1,1024,0,stream>>>(bsums, nb);
    scan_pass3<<<(n+255)/256,256,0,stream>>>(offs, bsums, n);
  };
  scan(cnt_dst, offs_dst, M);
  fill_csr_k<<<(E+255)/256,256,0,stream>>>(dst, src, offs_dst, fill_dst, sorted_dst, E);
  scan(cnt_src, offs_src, N);
  fill_csr_k<<<(E+255)/256,256,0,stream>>>(src, dst, offs_src, fill_src, sorted_src, E);
  scan(cnt_b, offs_b, B);
  fill_csr_k<<<(N+255)/256,256,0,stream>>>(batch, nullptr, offs_b, fill_b, sorted_b, N);

  const unsigned short* xin = Xb;
  for(int pi=0; pi<4; pi++){
    int n_rows = (pi & 1) ? M : N;       // rows of PMA input
    int nseg   = (pi & 1) ? N : M;       // pooled output rows
    const int* offs = (pi & 1) ? offs_src : offs_dst;
    const int* gl   = (pi & 1) ? sorted_src : sorted_dst;
    const unsigned short* WvT = WtAll + (size_t)0*262144 + (size_t)pi*65536;
    const unsigned short* W1T = WtAll + (size_t)1*262144 + (size_t)pi*65536;
    const unsigned short* W2T = WtAll + (size_t)2*262144 + (size_t)pi*65536;

    alpha_k<<<((size_t)n_rows*NHEAD+255)/256,256,0,stream>>>(
        xin, wattT + pi*NHEAD*D, batt + pi*NHEAD, alphaB, n_rows);
    dim3 gv((n_rows+127)/128, 2);
    gemm_mfma<false><<<gv,256,0,stream>>>(xin, WvT, bv + pi*D, bufV, n_rows);
    pma_pool<<<nseg,256,0,stream>>>(bufV, alphaB, offs, gl,
        att + pi*D, ln0g + pi*D, ln0b + pi*D, bufA, nseg);
    dim3 gt((nseg+127)/128, 2);
    gemm_mfma<true ><<<gt,256,0,stream>>>(bufA, W1T, b1 + pi*D, bufT, nseg);
    gemm_mfma<false><<<gt,256,0,stream>>>(bufT, W2T, b2 + pi*D, bufV, nseg);
    rff_tail<<<nseg,256,0,stream>>>(bufV, bufA, ln1g + pi*D, ln1b + pi*D, nseg);
    xin = bufA;
  }

  dim3 gr(B, 16);
  readout_acc<<<gr,256,0,stream>>>(bufA, offs_b, sorted_b, ro);
  classifier_k<<<B,128,0,stream>>>(ro, offs_b, cW1, cb1, clng, clnb, cW2, cb2, (float*)d_out);
}

// Round 3
// 1560.384 us; speedup vs baseline: 2.1977x; 1.3612x over previous
//
#include <hip/hip_runtime.h>
#include <stdint.h>
#include <stddef.h>

#define D 256
#define NHEAD 8

typedef short bf16x8 __attribute__((ext_vector_type(8)));
typedef float f32x4  __attribute__((ext_vector_type(4)));

__device__ __forceinline__ unsigned short f2b(float f){
  uint32_t u = __float_as_uint(f);
  u += 0x7FFF + ((u >> 16) & 1);
  return (unsigned short)(u >> 16);
}
__device__ __forceinline__ float b2f(unsigned int b){
  return __uint_as_float(b << 16);
}
__device__ __forceinline__ void gload_lds16(const void* g, void* l){
  __builtin_amdgcn_global_load_lds((const __attribute__((address_space(1))) void*)g,
                                   (__attribute__((address_space(3))) void*)l, 16, 0, 0);
}

// ---------------- CSR build ----------------
__global__ void hist_edges_k(const int* __restrict__ src, const int* __restrict__ dst,
                             int* cnt_src, int* cnt_dst, int E){
  int e = blockIdx.x*blockDim.x + threadIdx.x;
  if(e < E){ atomicAdd(&cnt_dst[dst[e]],1); atomicAdd(&cnt_src[src[e]],1); }
}
__global__ void hist_batch_k(const int* __restrict__ batch, int* cnt_b, int N){
  int i = blockIdx.x*blockDim.x + threadIdx.x;
  if(i < N) atomicAdd(&cnt_b[batch[i]],1);
}
__global__ void scan_pass1(const int* __restrict__ cnt, int* offs, int* bsums, int n){
  __shared__ int tmp[256];
  int g = blockIdx.x, t = threadIdx.x, i = g*256 + t;
  int v = (i < n) ? cnt[i] : 0;
  tmp[t] = v; __syncthreads();
  for(int off=1; off<256; off<<=1){
    int a = (t>=off) ? tmp[t-off] : 0; __syncthreads();
    tmp[t] += a; __syncthreads();
  }
  if(i < n) offs[i+1] = tmp[t];
  if(t == 255) bsums[g] = tmp[255];
}
__global__ void scan_pass2(int* bsums, int nb){
  __shared__ int tmp[1024];
  int t = threadIdx.x;
  int v = (t < nb) ? bsums[t] : 0;
  tmp[t] = v; __syncthreads();
  for(int off=1; off<1024; off<<=1){
    int a = (t>=off) ? tmp[t-off] : 0; __syncthreads();
    tmp[t] += a; __syncthreads();
  }
  if(t < nb) bsums[t] = tmp[t] - v;   // exclusive
}
__global__ void scan_pass3(int* offs, const int* bsums, int n){
  int i = blockIdx.x*blockDim.x + threadIdx.x;
  if(i == 0) offs[0] = 0;
  if(i < n) offs[i+1] += bsums[i>>8];
}
__global__ void fill_csr_k(const int* __restrict__ seg, const int* __restrict__ other,
                           const int* __restrict__ offs, int* fill, int* sorted, int E){
  int e = blockIdx.x*blockDim.x + threadIdx.x;
  if(e < E){
    int s = seg[e];
    int p = offs[s] + atomicAdd(&fill[s],1);
    sorted[p] = other ? other[e] : e;
  }
}

// ---------------- conversions ----------------
__global__ void conv_x_k(const float* __restrict__ X, unsigned short* __restrict__ Xb, int total8){
  int i = blockIdx.x*blockDim.x + threadIdx.x;
  if(i >= total8) return;
  float4 a = ((const float4*)X)[2*i], b = ((const float4*)X)[2*i+1];
  union { unsigned short u[8]; uint4 v; } o;
  o.u[0]=f2b(a.x); o.u[1]=f2b(a.y); o.u[2]=f2b(a.z); o.u[3]=f2b(a.w);
  o.u[4]=f2b(b.x); o.u[5]=f2b(b.y); o.u[6]=f2b(b.z); o.u[7]=f2b(b.w);
  ((uint4*)Xb)[i] = o.v;
}

// Wt[s][p][n][k] = W[p][k][n] bf16 via LDS tile transpose (coalesced both sides)
__global__ __launch_bounds__(256) void conv_wt_k(const float* __restrict__ Wv,
    const float* __restrict__ W1, const float* __restrict__ W2, unsigned short* __restrict__ Wt){
  __shared__ unsigned short lds[64][65];
  int sp = blockIdx.y; int s = sp >> 2, p = sp & 3;
  const float* W = (s==0?Wv:(s==1?W1:W2)) + (size_t)p*65536;
  int k0 = (blockIdx.x & 3)*64, n0 = (blockIdx.x >> 2)*64;
  for(int r=0;r<16;r++){
    int idx = r*256 + threadIdx.x;
    int row = idx >> 6, col = idx & 63;
    lds[col][row] = f2b(W[(size_t)(k0+row)*256 + n0+col]);
  }
  __syncthreads();
  unsigned short* out = Wt + (size_t)s*262144 + (size_t)p*65536;
  for(int r=0;r<16;r++){
    int idx = r*256 + threadIdx.x;
    int orow = idx >> 6, ocol = idx & 63;
    out[(size_t)(n0+orow)*256 + k0+ocol] = lds[orow][ocol];
  }
}

// ---------------- params prep: Wk_att = Wk @ att (per head), fp32 ----------------
__global__ void prep_watt_k(const float* __restrict__ Wk, const float* __restrict__ bk,
                            const float* __restrict__ att, float* __restrict__ wattT,
                            float* __restrict__ batt){
  int tid = blockIdx.x*blockDim.x + threadIdx.x;
  if(tid < 4*NHEAD*D){
    int c = tid & (D-1); int h = (tid>>8) & 7; int p = tid >> 11;
    const float* Wp = Wk + (size_t)p*D*D + (size_t)c*D + h*32;
    const float* ap = att + (size_t)p*D + h*32;
    float s = 0.f;
    #pragma unroll
    for(int d=0; d<32; d++) s += Wp[d]*ap[d];
    wattT[tid] = s;                       // [p][h][c]
  }
  if(tid < 4*NHEAD){
    int h = tid & 7, p = tid >> 3;
    const float* bp = bk + (size_t)p*D + h*32;
    const float* ap = att + (size_t)p*D + h*32;
    float s = 0.f;
    #pragma unroll
    for(int d=0; d<32; d++) s += bp[d]*ap[d];
    batt[tid] = s;
  }
}

// alpha[row,h] = Xb[row,:] . watt[h,:] + batt[h] ; X read once (broadcast across 8 h-threads)
__global__ __launch_bounds__(256) void alpha2_k(const unsigned short* __restrict__ X,
    const float* __restrict__ wattT, const float* __restrict__ batt,
    float* __restrict__ alpha, int n){
  __shared__ float wl[8][260];
  int t = threadIdx.x;
  for(int i=t;i<2048;i+=256) wl[i>>8][i&255] = wattT[i];
  __syncthreads();
  int r = t >> 3, h = t & 7;
  int row = blockIdx.x*32 + r;
  int crow = (row < n) ? row : (n-1);
  const uint4* xp = (const uint4*)(X + (size_t)crow*256);
  float acc = 0.f;
  #pragma unroll 4
  for(int c=0;c<32;c++){
    uint4 xv = xp[c];
    float4 w0 = *(const float4*)&wl[h][c*8];
    float4 w1 = *(const float4*)&wl[h][c*8+4];
    acc += b2f(xv.x&0xffff)*w0.x + b2f(xv.x>>16)*w0.y
         + b2f(xv.y&0xffff)*w0.z + b2f(xv.y>>16)*w0.w
         + b2f(xv.z&0xffff)*w1.x + b2f(xv.z>>16)*w1.y
         + b2f(xv.w&0xffff)*w1.z + b2f(xv.w>>16)*w1.w;
  }
  if(row < n) alpha[(size_t)row*8 + h] = acc + batt[h];
}

// ---------------- bf16 MFMA GEMM, A staged in LDS (swizzled), 64x256 tile ----------------
template<bool RELU>
__global__ __launch_bounds__(256) void gemm_mfma(const unsigned short* __restrict__ A,
    const unsigned short* __restrict__ Wt, const float* __restrict__ bias,
    unsigned short* __restrict__ C, int n){
  __shared__ unsigned short As[64*256];
  const int tid = threadIdx.x;
  const int row0 = blockIdx.x*64;
  #pragma unroll
  for(int i=0;i<8;i++){
    int a = i*4096 + tid*16;
    int row = a >> 9;
    int within = a & 511;
    int srcw = within ^ ((row & 7) << 4);       // pre-swizzled source (rule #21)
    int grow = row0 + row; grow = (grow < n) ? grow : (n-1);
    const void* gp = (const void*)((const char*)A + (size_t)grow*512 + srcw);
    void* lp = (void*)((char*)As + i*4096 + (tid & 192)*16);  // wave-uniform base
    gload_lds16(gp, lp);
  }
  __syncthreads();
  const int wc = tid >> 6;
  const int l  = tid & 63;
  const int lr = l & 15, lg = l >> 4;
  f32x4 acc[4][4] = {};
  const char* Asb = (const char*)As;
  #pragma unroll
  for(int k0=0; k0<256; k0+=32){
    bf16x8 af[4], bf_[4];
    #pragma unroll
    for(int mi=0;mi<4;mi++){
      int row = mi*16 + lr;
      int off = row*512 + ((k0*2 + lg*16) ^ ((row & 7) << 4));
      af[mi] = *(const bf16x8*)(Asb + off);
    }
    #pragma unroll
    for(int ni=0;ni<4;ni++){
      int col = wc*64 + ni*16 + lr;
      bf_[ni] = *(const bf16x8*)(Wt + (size_t)col*256 + k0 + lg*8);
    }
    #pragma unroll
    for(int mi=0;mi<4;mi++)
      #pragma unroll
      for(int ni=0;ni<4;ni++)
        acc[mi][ni] = __builtin_amdgcn_mfma_f32_16x16x32_bf16(af[mi], bf_[ni], acc[mi][ni], 0,0,0);
  }
  #pragma unroll
  for(int mi=0;mi<4;mi++){
    #pragma unroll
    for(int r4=0;r4<4;r4++){
      int row = row0 + mi*16 + lg*4 + r4;
      if(row >= n) continue;
      #pragma unroll
      for(int ni=0;ni<4;ni++){
        int col = wc*64 + ni*16 + lr;
        float v = acc[mi][ni][r4] + bias[col];
        if(RELU) v = fmaxf(v, 0.f);
        C[(size_t)row*256 + col] = f2b(v);
      }
    }
  }
}

// ---------------- block reductions ----------------
__device__ __forceinline__ float block_sum256(float v, float* red){
  #pragma unroll
  for(int m=32; m; m>>=1) v += __shfl_xor(v, m);
  if((threadIdx.x & 63) == 0) red[threadIdx.x >> 6] = v;
  __syncthreads();
  float s = red[0] + red[1] + red[2] + red[3];
  __syncthreads();
  return s;
}

// ---------------- per-segment softmax weights: w[pos,h]=exp(a-m), winv[s,h]=1/sum ----------------
__global__ __launch_bounds__(256) void pma_weights(const float* __restrict__ alpha,
    const int* __restrict__ offs, const int* __restrict__ glist,
    float* __restrict__ w, float* __restrict__ winv, int nseg){
  __shared__ float red[4][8];
  int s = blockIdx.x;
  int t = threadIdx.x;
  int h = t & 7, lane = t >> 3, wv = t >> 6;
  int e0 = offs[s], e1 = offs[s+1];
  float m = -3.0e38f;
  for(int pos = e0 + lane; pos < e1; pos += 32){
    float a = alpha[(size_t)glist[pos]*8 + h];
    a = (a > 0.f) ? a : 0.2f*a;
    m = fmaxf(m, a);
  }
  m = fmaxf(m, __shfl_xor(m, 8));
  m = fmaxf(m, __shfl_xor(m, 16));
  m = fmaxf(m, __shfl_xor(m, 32));
  if((t & 63) < 8) red[wv][h] = m;
  __syncthreads();
  m = fmaxf(fmaxf(red[0][h], red[1][h]), fmaxf(red[2][h], red[3][h]));
  float sum = 0.f;
  for(int pos = e0 + lane; pos < e1; pos += 32){
    float a = alpha[(size_t)glist[pos]*8 + h];
    a = (a > 0.f) ? a : 0.2f*a;
    float e = __expf(a - m);
    w[(size_t)pos*8 + h] = e;
    sum += e;
  }
  sum += __shfl_xor(sum, 8);
  sum += __shfl_xor(sum, 16);
  sum += __shfl_xor(sum, 32);
  __syncthreads();
  if((t & 63) < 8) red[wv][h] = sum;
  __syncthreads();
  if(t < 8){
    float tt = red[0][h] + red[1][h] + red[2][h] + red[3][h];
    winv[(size_t)s*8 + h] = 1.f / ((tt > 0.f) ? tt : 1.f);
  }
}

// ---------------- SpMM pool + residual + LN0 (4 edge-groups x 64 feat-threads) ----------------
__global__ __launch_bounds__(256) void pma_pool2(const unsigned short* __restrict__ V,
    const float* __restrict__ w, const float* __restrict__ winv,
    const int* __restrict__ offs, const int* __restrict__ glist,
    const float* __restrict__ attp, const float* __restrict__ g0, const float* __restrict__ b0,
    unsigned short* __restrict__ U, int nseg){
  __shared__ float part[4][256];
  __shared__ float red[4];
  int s = blockIdx.x;
  int t = threadIdx.x;
  int grp = t >> 6, ft = t & 63;
  int h = ft >> 3;
  int e0 = offs[s], e1 = offs[s+1];
  float4 acc = make_float4(0.f,0.f,0.f,0.f);
  int pos = e0 + grp;
  int g = 0; float wv = 0.f;
  if(pos < e1){ g = glist[pos]; wv = w[(size_t)pos*8 + h]; }
  while(pos < e1){
    int pos2 = pos + 4;
    int g2 = 0; float wv2 = 0.f;
    if(pos2 < e1){ g2 = glist[pos2]; wv2 = w[(size_t)pos2*8 + h]; }
    uint2 v = *(const uint2*)(V + (size_t)g*256 + ft*4);
    acc.x += wv * b2f(v.x & 0xffff);
    acc.y += wv * b2f(v.x >> 16);
    acc.z += wv * b2f(v.y & 0xffff);
    acc.w += wv * b2f(v.y >> 16);
    pos = pos2; g = g2; wv = wv2;
  }
  *(float4*)&part[grp][ft*4] = acc;
  __syncthreads();
  int f = t;
  float sum = part[0][f] + part[1][f] + part[2][f] + part[3][f];
  float out = sum * winv[(size_t)s*8 + (f>>5)] + attp[f];
  float mu  = block_sum256(out, red) * (1.f/256.f);
  float dd  = out - mu;
  float var = block_sum256(dd*dd, red) * (1.f/256.f);
  U[(size_t)s*256 + f] = f2b(dd * rsqrtf(var + 1e-5f) * g0[f] + b0[f]);
}

// ---------------- rFF tail: X = relu(LN1(U + relu(R))), wave-per-row vectorized ----------------
__global__ __launch_bounds__(256) void rff_tail(const unsigned short* __restrict__ R,
    unsigned short* __restrict__ U,
    const float* __restrict__ g1, const float* __restrict__ b1p, int nseg){
  int s = blockIdx.x*4 + (threadIdx.x >> 6);
  if(s >= nseg) return;
  int l = threadIdx.x & 63;
  uint2 uv = *(const uint2*)(U + (size_t)s*256 + l*4);
  uint2 rv = *(const uint2*)(R + (size_t)s*256 + l*4);
  float v0 = b2f(uv.x & 0xffff) + fmaxf(b2f(rv.x & 0xffff), 0.f);
  float v1 = b2f(uv.x >> 16)    + fmaxf(b2f(rv.x >> 16),    0.f);
  float v2 = b2f(uv.y & 0xffff) + fmaxf(b2f(rv.y & 0xffff), 0.f);
  float v3 = b2f(uv.y >> 16)    + fmaxf(b2f(rv.y >> 16),    0.f);
  float sum = v0+v1+v2+v3;
  #pragma unroll
  for(int m=32; m; m>>=1) sum += __shfl_xor(sum, m);
  float mu = sum * (1.f/256.f);
  float d0 = v0-mu, d1 = v1-mu, d2 = v2-mu, d3 = v3-mu;
  float sq = d0*d0 + d1*d1 + d2*d2 + d3*d3;
  #pragma unroll
  for(int m=32; m; m>>=1) sq += __shfl_xor(sq, m);
  float rs = rsqrtf(sq * (1.f/256.f) + 1e-5f);
  float4 gg = *(const float4*)(g1 + l*4);
  float4 bb = *(const float4*)(b1p + l*4);
  unsigned short o0 = f2b(fmaxf(d0*rs*gg.x + bb.x, 0.f));
  unsigned short o1 = f2b(fmaxf(d1*rs*gg.y + bb.y, 0.f));
  unsigned short o2 = f2b(fmaxf(d2*rs*gg.z + bb.z, 0.f));
  unsigned short o3 = f2b(fmaxf(d3*rs*gg.w + bb.w, 0.f));
  uint2 ov; ov.x = (uint32_t)o0 | ((uint32_t)o1 << 16); ov.y = (uint32_t)o2 | ((uint32_t)o3 << 16);
  *(uint2*)(U + (size_t)s*256 + l*4) = ov;
}

// ---------------- readout: chunked segment-sum with atomics ----------------
__global__ __launch_bounds__(256) void readout_acc(const unsigned short* __restrict__ X,
    const int* __restrict__ offsb, const int* __restrict__ nidx, float* __restrict__ ro){
  int b = blockIdx.x, chunk = blockIdx.y, t = threadIdx.x;
  int e0 = offsb[b], e1 = offsb[b+1];
  int len = e1 - e0;
  int per = (len + gridDim.y - 1) / gridDim.y;
  int s0 = e0 + chunk*per;
  int s1 = min(s0 + per, e1);
  if(s0 >= s1) return;
  float s = 0.f;
  for(int i=s0; i<s1; i++) s += b2f((unsigned int)X[(size_t)nidx[i]*256 + t]);
  atomicAdd(&ro[b*256 + t], s);
}

// ---------------- classifier ----------------
__global__ __launch_bounds__(128) void classifier_k(const float* __restrict__ ro,
    const int* __restrict__ offsb,
    const float* __restrict__ cW1, const float* __restrict__ cb1,
    const float* __restrict__ clng, const float* __restrict__ clnb,
    const float* __restrict__ cW2, const float* __restrict__ cb2, float* __restrict__ out){
  __shared__ float xs[256];
  __shared__ float hs[128];
  __shared__ float red[2];
  int b = blockIdx.x, j = threadIdx.x;
  int cnt = offsb[b+1] - offsb[b];
  float sc = 1.f / ((cnt > 0) ? (float)cnt : 1.f);
  xs[j] = ro[b*256 + j]*sc; xs[j+128] = ro[b*256 + j + 128]*sc;
  __syncthreads();
  float hv = cb1[j];
  for(int c=0; c<256; c++) hv += xs[c]*cW1[c*128 + j];
  float v = hv;
  #pragma unroll
  for(int mm=32; mm; mm>>=1) v += __shfl_xor(v, mm);
  if((j & 63) == 0) red[j>>6] = v;
  __syncthreads();
  float mu = (red[0] + red[1]) * (1.f/128.f);
  __syncthreads();
  float dd = hv - mu;
  v = dd*dd;
  #pragma unroll
  for(int mm=32; mm; mm>>=1) v += __shfl_xor(v, mm);
  if((j & 63) == 0) red[j>>6] = v;
  __syncthreads();
  float var = (red[0] + red[1]) * (1.f/128.f);
  float hn = fmaxf(dd * rsqrtf(var + 1e-5f) * clng[j] + clnb[j], 0.f);
  hs[j] = hn;
  __syncthreads();
  if(j < 10){
    float o = cb2[j];
    #pragma unroll
    for(int c=0; c<128; c++) o += hs[c]*cW2[c*10 + j];
    out[b*10 + j] = o;
  }
}

extern "C" void kernel_launch(void* const* d_in, const int* in_sizes, int n_in,
                              void* d_out, int out_size, void* d_ws, size_t ws_size,
                              hipStream_t stream){
  const float* X0   = (const float*)d_in[0];
  const int*   src  = (const int*)d_in[1];
  const int*   dst  = (const int*)d_in[2];
  const int*   batch= (const int*)d_in[3];
  const float* Wk   = (const float*)d_in[6];
  const float* bk   = (const float*)d_in[7];
  const float* Wv   = (const float*)d_in[8];
  const float* bv   = (const float*)d_in[9];
  const float* att  = (const float*)d_in[10];
  const float* ln0g = (const float*)d_in[11];
  const float* ln0b = (const float*)d_in[12];
  const float* ln1g = (const float*)d_in[13];
  const float* ln1b = (const float*)d_in[14];
  const float* W1   = (const float*)d_in[15];
  const float* b1   = (const float*)d_in[16];
  const float* W2   = (const float*)d_in[17];
  const float* b2   = (const float*)d_in[18];
  const float* cW1  = (const float*)d_in[19];
  const float* cb1  = (const float*)d_in[20];
  const float* clng = (const float*)d_in[21];
  const float* clnb = (const float*)d_in[22];
  const float* cW2  = (const float*)d_in[23];
  const float* cb2  = (const float*)d_in[24];

  const int N = in_sizes[0] / D;     // 100000
  const int E = in_sizes[1];         // 400000
  const int M = 20000, B = 64;

  char* p = (char*)d_ws;
  auto carve = [&](size_t bytes)->void*{
    void* r = (void*)p; p += (bytes + 255) & ~(size_t)255; return r;
  };
  unsigned short* Xb   = (unsigned short*)carve((size_t)N*D*2);
  unsigned short* bufA = (unsigned short*)carve((size_t)N*D*2);
  unsigned short* bufV = (unsigned short*)carve((size_t)N*D*2);
  unsigned short* bufT = (unsigned short*)carve((size_t)N*D*2);
  unsigned short* WtAll= (unsigned short*)carve((size_t)3*4*65536*2);
  float* wE     = (float*)carve((size_t)E*8*4);
  float* winv   = (float*)carve((size_t)N*8*4);
  float* alphaB = (float*)carve((size_t)N*8*4);
  float* wattT  = (float*)carve(4*NHEAD*D*4);
  float* batt   = (float*)carve(4*NHEAD*4);
  int* offs_dst = (int*)carve((size_t)(M+1)*4);
  int* offs_src = (int*)carve((size_t)(N+1)*4);
  int* offs_b   = (int*)carve((size_t)(B+1)*4);
  int* sorted_dst = (int*)carve((size_t)E*4);
  int* sorted_src = (int*)carve((size_t)E*4);
  int* sorted_b   = (int*)carve((size_t)N*4);
  int* bsums    = (int*)carve(1024*4);
  char* z0 = p;                       // contiguous zero-init block
  int* cnt_dst = (int*)carve((size_t)M*4);
  int* cnt_src = (int*)carve((size_t)N*4);
  int* cnt_b   = (int*)carve((size_t)B*4);
  int* fill_dst= (int*)carve((size_t)M*4);
  int* fill_src= (int*)carve((size_t)N*4);
  int* fill_b  = (int*)carve((size_t)B*4);
  float* ro    = (float*)carve((size_t)B*D*4);
  size_t zbytes = (size_t)(p - z0);
  hipMemsetAsync(z0, 0, zbytes, stream);

  // conversions
  conv_x_k<<<(N*D/8+255)/256,256,0,stream>>>(X0, Xb, N*D/8);
  dim3 gw(16, 12);
  conv_wt_k<<<gw,256,0,stream>>>(Wv, W1, W2, WtAll);
  prep_watt_k<<<(4*NHEAD*D+255)/256,256,0,stream>>>(Wk, bk, att, wattT, batt);

  // CSR builds
  hist_edges_k<<<(E+255)/256,256,0,stream>>>(src, dst, cnt_src, cnt_dst, E);
  hist_batch_k<<<(N+255)/256,256,0,stream>>>(batch, cnt_b, N);
  auto scan = [&](const int* cnt, int* offs, int n){
    int nb = (n+255)/256;
    scan_pass1<<<nb,256,0,stream>>>(cnt, offs, bsums, n);
    scan_pass2<<<1,1024,0,stream>>>(bsums, nb);
    scan_pass3<<<(n+255)/256,256,0,stream>>>(offs, bsums, n);
  };
  scan(cnt_dst, offs_dst, M);
  fill_csr_k<<<(E+255)/256,256,0,stream>>>(dst, src, offs_dst, fill_dst, sorted_dst, E);
  scan(cnt_src, offs_src, N);
  fill_csr_k<<<(E+255)/256,256,0,stream>>>(src, dst, offs_src, fill_src, sorted_src, E);
  scan(cnt_b, offs_b, B);
  fill_csr_k<<<(N+255)/256,256,0,stream>>>(batch, nullptr, offs_b, fill_b, sorted_b, N);

  const unsigned short* xin = Xb;
  for(int pi=0; pi<4; pi++){
    int n_rows = (pi & 1) ? M : N;
    int nseg   = (pi & 1) ? N : M;
    const int* offs = (pi & 1) ? offs_src : offs_dst;
    const int* gl   = (pi & 1) ? sorted_src : sorted_dst;
    const unsigned short* WvT = WtAll + (size_t)0*262144 + (size_t)pi*65536;
    const unsigned short* W1T = WtAll + (size_t)1*262144 + (size_t)pi*65536;
    const unsigned short* W2T = WtAll + (size_t)2*262144 + (size_t)pi*65536;

    alpha2_k<<<(n_rows+31)/32,256,0,stream>>>(xin, wattT + pi*NHEAD*D, batt + pi*NHEAD, alphaB, n_rows);
    gemm_mfma<false><<<(n_rows+63)/64,256,0,stream>>>(xin, WvT, bv + pi*D, bufV, n_rows);
    pma_weights<<<nseg,256,0,stream>>>(alphaB, offs, gl, wE, winv, nseg);
    pma_pool2<<<nseg,256,0,stream>>>(bufV, wE, winv, offs, gl,
        att + pi*D, ln0g + pi*D, ln0b + pi*D, bufA, nseg);
    gemm_mfma<true ><<<(nseg+63)/64,256,0,stream>>>(bufA, W1T, b1 + pi*D, bufT, nseg);
    gemm_mfma<false><<<(nseg+63)/64,256,0,stream>>>(bufT, W2T, b2 + pi*D, bufV, nseg);
    rff_tail<<<(nseg+3)/4,256,0,stream>>>(bufV, bufA, ln1g + pi*D, ln1b + pi*D, nseg);
    xin = bufA;
  }

  dim3 gr(B, 16);
  readout_acc<<<gr,256,0,stream>>>(bufA, offs_b, sorted_b, ro);
  classifier_k<<<B,128,0,stream>>>(ro, offs_b, cW1, cb1, clng, clnb, cW2, cb2, (float*)d_out);
}

// Round 4
// 1136.415 us; speedup vs baseline: 3.0175x; 1.3731x over previous
//
#include <hip/hip_runtime.h>
#include <stdint.h>
#include <stddef.h>

#define D 256
#define NHEAD 8

typedef short bf16x8 __attribute__((ext_vector_type(8)));
typedef float f32x4  __attribute__((ext_vector_type(4)));

__device__ __forceinline__ unsigned short f2b(float f){
  uint32_t u = __float_as_uint(f);
  u += 0x7FFF + ((u >> 16) & 1);
  return (unsigned short)(u >> 16);
}
__device__ __forceinline__ float b2f(unsigned int b){
  return __uint_as_float(b << 16);
}
__device__ __forceinline__ void gload_lds16(const void* g, void* l){
  __builtin_amdgcn_global_load_lds((const __attribute__((address_space(1))) void*)g,
                                   (__attribute__((address_space(3))) void*)l, 16, 0, 0);
}

// ---------------- CSR build (edges: atomic fill; contention <= 20-way, fine) ----------------
__global__ void hist_edges_k(const int* __restrict__ src, const int* __restrict__ dst,
                             int* cnt_src, int* cnt_dst, int E){
  int e = blockIdx.x*blockDim.x + threadIdx.x;
  if(e < E){ atomicAdd(&cnt_dst[dst[e]],1); atomicAdd(&cnt_src[src[e]],1); }
}
__global__ void scan_pass1(const int* __restrict__ cnt, int* offs, int* bsums, int n){
  __shared__ int tmp[256];
  int g = blockIdx.x, t = threadIdx.x, i = g*256 + t;
  int v = (i < n) ? cnt[i] : 0;
  tmp[t] = v; __syncthreads();
  for(int off=1; off<256; off<<=1){
    int a = (t>=off) ? tmp[t-off] : 0; __syncthreads();
    tmp[t] += a; __syncthreads();
  }
  if(i < n) offs[i+1] = tmp[t];
  if(t == 255) bsums[g] = tmp[255];
}
__global__ void scan_pass2(int* bsums, int nb){
  __shared__ int tmp[1024];
  int t = threadIdx.x;
  int v = (t < nb) ? bsums[t] : 0;
  tmp[t] = v; __syncthreads();
  for(int off=1; off<1024; off<<=1){
    int a = (t>=off) ? tmp[t-off] : 0; __syncthreads();
    tmp[t] += a; __syncthreads();
  }
  if(t < nb) bsums[t] = tmp[t] - v;   // exclusive
}
__global__ void scan_pass3(int* offs, const int* bsums, int n){
  int i = blockIdx.x*blockDim.x + threadIdx.x;
  if(i == 0) offs[0] = 0;
  if(i < n) offs[i+1] += bsums[i>>8];
}
__global__ void fill_csr_k(const int* __restrict__ seg, const int* __restrict__ other,
                           const int* __restrict__ offs, int* fill, int* sorted, int E){
  int e = blockIdx.x*blockDim.x + threadIdx.x;
  if(e < E){
    int s = seg[e];
    int p = offs[s] + atomicAdd(&fill[s],1);
    sorted[p] = other[e];
  }
}

// ---------------- batch CSR via counting sort (64 hot addrs -> LDS hist + scan) ----------------
__global__ __launch_bounds__(256) void bhist_k(const int* __restrict__ batch, int* __restrict__ gcnt,
                                               int N, int nb){
  __shared__ int h[64];
  int t = threadIdx.x, blk = blockIdx.x;
  if(t < 64) h[t] = 0;
  __syncthreads();
  int i = blk*256 + t;
  if(i < N) atomicAdd(&h[batch[i]], 1);
  __syncthreads();
  if(t < 64) gcnt[t*nb + blk] = h[t];
}
__global__ void boffs_fin(const int* __restrict__ boffs, int* __restrict__ offs_b, int nb, int N){
  int t = threadIdx.x;
  if(t < 64) offs_b[t] = boffs[t*nb];
  if(t == 64) offs_b[64] = N;
}
__global__ __launch_bounds__(256) void bfill_k(const int* __restrict__ batch,
    const int* __restrict__ boffs, int* __restrict__ sorted_b, int N, int nb){
  __shared__ int base[64];
  __shared__ int cnt[64];
  int t = threadIdx.x, blk = blockIdx.x;
  if(t < 64){ base[t] = boffs[t*nb + blk]; cnt[t] = 0; }
  __syncthreads();
  int i = blk*256 + t;
  if(i < N){
    int b = batch[i];
    int r = atomicAdd(&cnt[b], 1);      // LDS atomic, ~4-way avg contention
    sorted_b[base[b] + r] = i;
  }
}

// ---------------- conversions ----------------
__global__ void conv_x_k(const float* __restrict__ X, unsigned short* __restrict__ Xb, int total8){
  int i = blockIdx.x*blockDim.x + threadIdx.x;
  if(i >= total8) return;
  float4 a = ((const float4*)X)[2*i], b = ((const float4*)X)[2*i+1];
  union { unsigned short u[8]; uint4 v; } o;
  o.u[0]=f2b(a.x); o.u[1]=f2b(a.y); o.u[2]=f2b(a.z); o.u[3]=f2b(a.w);
  o.u[4]=f2b(b.x); o.u[5]=f2b(b.y); o.u[6]=f2b(b.z); o.u[7]=f2b(b.w);
  ((uint4*)Xb)[i] = o.v;
}

// Wt[s][p][n][k] = W[p][k][n] bf16 via LDS tile transpose (coalesced both sides)
__global__ __launch_bounds__(256) void conv_wt_k(const float* __restrict__ Wv,
    const float* __restrict__ W1, const float* __restrict__ W2, unsigned short* __restrict__ Wt){
  __shared__ unsigned short lds[64][65];
  int sp = blockIdx.y; int s = sp >> 2, p = sp & 3;
  const float* W = (s==0?Wv:(s==1?W1:W2)) + (size_t)p*65536;
  int k0 = (blockIdx.x & 3)*64, n0 = (blockIdx.x >> 2)*64;
  for(int r=0;r<16;r++){
    int idx = r*256 + threadIdx.x;
    int row = idx >> 6, col = idx & 63;
    lds[col][row] = f2b(W[(size_t)(k0+row)*256 + n0+col]);
  }
  __syncthreads();
  unsigned short* out = Wt + (size_t)s*262144 + (size_t)p*65536;
  for(int r=0;r<16;r++){
    int idx = r*256 + threadIdx.x;
    int orow = idx >> 6, ocol = idx & 63;
    out[(size_t)(n0+orow)*256 + k0+ocol] = lds[orow][ocol];
  }
}

// ---------------- params prep: wattb[p][16][256] bf16 (h>=8 rows pre-zeroed), batt fp32 ----------------
__global__ void prep_watt_k(const float* __restrict__ Wk, const float* __restrict__ bk,
                            const float* __restrict__ att, unsigned short* __restrict__ wattb,
                            float* __restrict__ batt){
  int tid = blockIdx.x*blockDim.x + threadIdx.x;
  if(tid < 4*NHEAD*D){
    int c = tid & (D-1); int h = (tid>>8) & 7; int p = tid >> 11;
    const float* Wp = Wk + (size_t)p*D*D + (size_t)c*D + h*32;
    const float* ap = att + (size_t)p*D + h*32;
    float s = 0.f;
    #pragma unroll
    for(int d=0; d<32; d++) s += Wp[d]*ap[d];
    wattb[((size_t)(p*16 + h))*256 + c] = f2b(s);
  }
  if(tid < 4*NHEAD){
    int h = tid & 7, p = tid >> 3;
    const float* bp = bk + (size_t)p*D + h*32;
    const float* ap = att + (size_t)p*D + h*32;
    float s = 0.f;
    #pragma unroll
    for(int d=0; d<32; d++) s += bp[d]*ap[d];
    batt[tid] = s;
  }
}

// ---------------- V-GEMM + fused alpha: C=A@Wv+bv (bf16), alpha=A@wattb+batt (fp32) ----------------
__global__ __launch_bounds__(256) void gemm_valpha(const unsigned short* __restrict__ A,
    const unsigned short* __restrict__ Wt, const float* __restrict__ bias,
    const unsigned short* __restrict__ wattb, const float* __restrict__ batt8,
    unsigned short* __restrict__ C, float* __restrict__ alpha, int n){
  __shared__ unsigned short As[64*256];
  const int tid = threadIdx.x;
  const int row0 = blockIdx.x*64;
  #pragma unroll
  for(int i=0;i<8;i++){
    int a = i*4096 + tid*16;
    int row = a >> 9;
    int within = a & 511;
    int srcw = within ^ ((row & 7) << 4);
    int grow = row0 + row; grow = (grow < n) ? grow : (n-1);
    const void* gp = (const void*)((const char*)A + (size_t)grow*512 + srcw);
    void* lp = (void*)((char*)As + i*4096 + (tid & 192)*16);
    gload_lds16(gp, lp);
  }
  __syncthreads();
  const int wc = tid >> 6;
  const int l  = tid & 63;
  const int lr = l & 15, lg = l >> 4;
  f32x4 acc[4][4] = {};
  f32x4 accw = {0.f,0.f,0.f,0.f};
  const char* Asb = (const char*)As;
  const int roww = wc*16 + lr;
  #pragma unroll
  for(int k0=0; k0<256; k0+=32){
    bf16x8 af[4], bf_[4];
    #pragma unroll
    for(int mi=0;mi<4;mi++){
      int row = mi*16 + lr;
      af[mi] = *(const bf16x8*)(Asb + row*512 + ((k0*2 + lg*16) ^ ((row & 7) << 4)));
    }
    #pragma unroll
    for(int ni=0;ni<4;ni++){
      int col = wc*64 + ni*16 + lr;
      bf_[ni] = *(const bf16x8*)(Wt + (size_t)col*256 + k0 + lg*8);
    }
    bf16x8 afw = *(const bf16x8*)(Asb + roww*512 + ((k0*2 + lg*16) ^ ((roww & 7) << 4)));
    bf16x8 bfw = *(const bf16x8*)((const char*)wattb + lr*512 + k0*2 + lg*16);
    #pragma unroll
    for(int mi=0;mi<4;mi++)
      #pragma unroll
      for(int ni=0;ni<4;ni++)
        acc[mi][ni] = __builtin_amdgcn_mfma_f32_16x16x32_bf16(af[mi], bf_[ni], acc[mi][ni], 0,0,0);
    accw = __builtin_amdgcn_mfma_f32_16x16x32_bf16(afw, bfw, accw, 0,0,0);
  }
  // alpha epilogue: wave wc owns rows wc*16..wc*16+15, head = lr (<8)
  #pragma unroll
  for(int r4=0;r4<4;r4++){
    int grow = row0 + wc*16 + lg*4 + r4;
    if(lr < 8 && grow < n) alpha[(size_t)grow*8 + lr] = accw[r4] + batt8[lr];
  }
  #pragma unroll
  for(int mi=0;mi<4;mi++){
    #pragma unroll
    for(int r4=0;r4<4;r4++){
      int row = row0 + mi*16 + lg*4 + r4;
      if(row >= n) continue;
      #pragma unroll
      for(int ni=0;ni<4;ni++){
        int col = wc*64 + ni*16 + lr;
        C[(size_t)row*256 + col] = f2b(acc[mi][ni][r4] + bias[col]);
      }
    }
  }
}

// ---------------- fused rFF: U = relu(LN1(U + relu(relu(U@W1+b1)@W2+b2))), in-place ----------------
__global__ __launch_bounds__(256) void rff_fused(unsigned short* __restrict__ U,
    const unsigned short* __restrict__ W1t, const float* __restrict__ b1p,
    const unsigned short* __restrict__ W2t, const float* __restrict__ b2p,
    const float* __restrict__ g1, const float* __restrict__ b1n, int n){
  __shared__ unsigned short As[64*256];
  __shared__ unsigned short Hs[64*256];
  __shared__ float rsum[64][4];
  __shared__ float muv[64];
  __shared__ float rsv[64];
  const int tid = threadIdx.x;
  const int row0 = blockIdx.x*64;
  #pragma unroll
  for(int i=0;i<8;i++){
    int a = i*4096 + tid*16;
    int row = a >> 9;
    int within = a & 511;
    int srcw = within ^ ((row & 7) << 4);
    int grow = row0 + row; grow = (grow < n) ? grow : (n-1);
    const void* gp = (const void*)((const char*)U + (size_t)grow*512 + srcw);
    void* lp = (void*)((char*)As + i*4096 + (tid & 192)*16);
    gload_lds16(gp, lp);
  }
  __syncthreads();
  const int wc = tid >> 6;
  const int l  = tid & 63;
  const int lr = l & 15, lg = l >> 4;
  const char* Asb = (const char*)As;
  char* Hsb = (char*)Hs;
  float bias1[4], bias2[4], gg[4], bb[4];
  #pragma unroll
  for(int ni=0;ni<4;ni++){
    int col = wc*64 + ni*16 + lr;
    bias1[ni] = b1p[col]; bias2[ni] = b2p[col]; gg[ni] = g1[col]; bb[ni] = b1n[col];
  }
  const f32x4 zz = {0.f,0.f,0.f,0.f};
  f32x4 acc[4][4] = {};
  // GEMM1: H = relu(A@W1 + b1)
  #pragma unroll
  for(int k0=0; k0<256; k0+=32){
    bf16x8 af[4], bf_[4];
    #pragma unroll
    for(int mi=0;mi<4;mi++){
      int row = mi*16 + lr;
      af[mi] = *(const bf16x8*)(Asb + row*512 + ((k0*2 + lg*16) ^ ((row & 7) << 4)));
    }
    #pragma unroll
    for(int ni=0;ni<4;ni++){
      int col = wc*64 + ni*16 + lr;
      bf_[ni] = *(const bf16x8*)(W1t + (size_t)col*256 + k0 + lg*8);
    }
    #pragma unroll
    for(int mi=0;mi<4;mi++)
      #pragma unroll
      for(int ni=0;ni<4;ni++)
        acc[mi][ni] = __builtin_amdgcn_mfma_f32_16x16x32_bf16(af[mi], bf_[ni], acc[mi][ni], 0,0,0);
  }
  // write H to LDS (swizzled 2B stores)
  #pragma unroll
  for(int mi=0;mi<4;mi++)
    #pragma unroll
    for(int ni=0;ni<4;ni++){
      int col = wc*64 + ni*16 + lr;
      #pragma unroll
      for(int r4=0;r4<4;r4++){
        int row = mi*16 + lg*4 + r4;
        *(unsigned short*)(Hsb + row*512 + ((col*2) ^ ((row & 7) << 4))) =
            f2b(fmaxf(acc[mi][ni][r4] + bias1[ni], 0.f));
      }
    }
  __syncthreads();
  // GEMM2: R = H@W2 + b2
  #pragma unroll
  for(int mi=0;mi<4;mi++)
    #pragma unroll
    for(int ni=0;ni<4;ni++)
      acc[mi][ni] = zz;
  #pragma unroll
  for(int k0=0; k0<256; k0+=32){
    bf16x8 af[4], bf_[4];
    #pragma unroll
    for(int mi=0;mi<4;mi++){
      int row = mi*16 + lr;
      af[mi] = *(const bf16x8*)(Hsb + row*512 + ((k0*2 + lg*16) ^ ((row & 7) << 4)));
    }
    #pragma unroll
    for(int ni=0;ni<4;ni++){
      int col = wc*64 + ni*16 + lr;
      bf_[ni] = *(const bf16x8*)(W2t + (size_t)col*256 + k0 + lg*8);
    }
    #pragma unroll
    for(int mi=0;mi<4;mi++)
      #pragma unroll
      for(int ni=0;ni<4;ni++)
        acc[mi][ni] = __builtin_amdgcn_mfma_f32_16x16x32_bf16(af[mi], bf_[ni], acc[mi][ni], 0,0,0);
  }
  // v = U + relu(R)  (U re-read from As in LDS)
  f32x4 v[4][4];
  #pragma unroll
  for(int mi=0;mi<4;mi++)
    #pragma unroll
    for(int ni=0;ni<4;ni++){
      int col = wc*64 + ni*16 + lr;
      #pragma unroll
      for(int r4=0;r4<4;r4++){
        int row = mi*16 + lg*4 + r4;
        unsigned short u = *(const unsigned short*)(Asb + row*512 + ((col*2) ^ ((row & 7) << 4)));
        v[mi][ni][r4] = b2f(u) + fmaxf(acc[mi][ni][r4] + bias2[ni], 0.f);
      }
    }
  // row means
  f32x4 rp[4];
  #pragma unroll
  for(int mi=0;mi<4;mi++){
    rp[mi] = v[mi][0] + v[mi][1] + v[mi][2] + v[mi][3];
    #pragma unroll
    for(int c=0;c<4;c++){
      float x = rp[mi][c];
      x += __shfl_xor(x, 1); x += __shfl_xor(x, 2);
      x += __shfl_xor(x, 4); x += __shfl_xor(x, 8);
      rp[mi][c] = x;
    }
  }
  if(lr == 0){
    #pragma unroll
    for(int mi=0;mi<4;mi++)
      #pragma unroll
      for(int r4=0;r4<4;r4++)
        rsum[mi*16 + lg*4 + r4][wc] = rp[mi][r4];
  }
  __syncthreads();
  if(tid < 64) muv[tid] = (rsum[tid][0]+rsum[tid][1]+rsum[tid][2]+rsum[tid][3]) * (1.f/256.f);
  __syncthreads();
  #pragma unroll
  for(int mi=0;mi<4;mi++)
    #pragma unroll
    for(int ni=0;ni<4;ni++)
      #pragma unroll
      for(int r4=0;r4<4;r4++){
        int row = mi*16 + lg*4 + r4;
        v[mi][ni][r4] -= muv[row];
      }
  #pragma unroll
  for(int mi=0;mi<4;mi++){
    rp[mi] = v[mi][0]*v[mi][0] + v[mi][1]*v[mi][1] + v[mi][2]*v[mi][2] + v[mi][3]*v[mi][3];
    #pragma unroll
    for(int c=0;c<4;c++){
      float x = rp[mi][c];
      x += __shfl_xor(x, 1); x += __shfl_xor(x, 2);
      x += __shfl_xor(x, 4); x += __shfl_xor(x, 8);
      rp[mi][c] = x;
    }
  }
  if(lr == 0){
    #pragma unroll
    for(int mi=0;mi<4;mi++)
      #pragma unroll
      for(int r4=0;r4<4;r4++)
        rsum[mi*16 + lg*4 + r4][wc] = rp[mi][r4];
  }
  __syncthreads();
  if(tid < 64) rsv[tid] = rsqrtf((rsum[tid][0]+rsum[tid][1]+rsum[tid][2]+rsum[tid][3]) * (1.f/256.f) + 1e-5f);
  __syncthreads();
  #pragma unroll
  for(int mi=0;mi<4;mi++)
    #pragma unroll
    for(int ni=0;ni<4;ni++){
      int col = wc*64 + ni*16 + lr;
      #pragma unroll
      for(int r4=0;r4<4;r4++){
        int row = mi*16 + lg*4 + r4;
        int grow = row0 + row;
        if(grow < n)
          U[(size_t)grow*256 + col] = f2b(fmaxf(v[mi][ni][r4]*rsv[row]*gg[ni] + bb[ni], 0.f));
      }
    }
}

// ---------------- block reductions ----------------
__device__ __forceinline__ float block_sum256(float v, float* red){
  #pragma unroll
  for(int m=32; m; m>>=1) v += __shfl_xor(v, m);
  if((threadIdx.x & 63) == 0) red[threadIdx.x >> 6] = v;
  __syncthreads();
  float s = red[0] + red[1] + red[2] + red[3];
  __syncthreads();
  return s;
}

// ---------------- per-segment softmax weights ----------------
__global__ __launch_bounds__(256) void pma_weights(const float* __restrict__ alpha,
    const int* __restrict__ offs, const int* __restrict__ glist,
    float* __restrict__ w, float* __restrict__ winv, int nseg){
  __shared__ float red[4][8];
  int s = blockIdx.x;
  int t = threadIdx.x;
  int h = t & 7, lane = t >> 3, wv = t >> 6;
  int e0 = offs[s], e1 = offs[s+1];
  float m = -3.0e38f;
  for(int pos = e0 + lane; pos < e1; pos += 32){
    float a = alpha[(size_t)glist[pos]*8 + h];
    a = (a > 0.f) ? a : 0.2f*a;
    m = fmaxf(m, a);
  }
  m = fmaxf(m, __shfl_xor(m, 8));
  m = fmaxf(m, __shfl_xor(m, 16));
  m = fmaxf(m, __shfl_xor(m, 32));
  if((t & 63) < 8) red[wv][h] = m;
  __syncthreads();
  m = fmaxf(fmaxf(red[0][h], red[1][h]), fmaxf(red[2][h], red[3][h]));
  float sum = 0.f;
  for(int pos = e0 + lane; pos < e1; pos += 32){
    float a = alpha[(size_t)glist[pos]*8 + h];
    a = (a > 0.f) ? a : 0.2f*a;
    float e = __expf(a - m);
    w[(size_t)pos*8 + h] = e;
    sum += e;
  }
  sum += __shfl_xor(sum, 8);
  sum += __shfl_xor(sum, 16);
  sum += __shfl_xor(sum, 32);
  __syncthreads();
  if((t & 63) < 8) red[wv][h] = sum;
  __syncthreads();
  if(t < 8){
    float tt = red[0][h] + red[1][h] + red[2][h] + red[3][h];
    winv[(size_t)s*8 + h] = 1.f / ((tt > 0.f) ? tt : 1.f);
  }
}

// ---------------- SpMM pool + residual + LN0 ----------------
__global__ __launch_bounds__(256) void pma_pool2(const unsigned short* __restrict__ V,
    const float* __restrict__ w, const float* __restrict__ winv,
    const int* __restrict__ offs, const int* __restrict__ glist,
    const float* __restrict__ attp, const float* __restrict__ g0, const float* __restrict__ b0,
    unsigned short* __restrict__ U, int nseg){
  __shared__ float part[4][256];
  __shared__ float red[4];
  int s = blockIdx.x;
  int t = threadIdx.x;
  int grp = t >> 6, ft = t & 63;
  int h = ft >> 3;
  int e0 = offs[s], e1 = offs[s+1];
  float4 acc = make_float4(0.f,0.f,0.f,0.f);
  int pos = e0 + grp;
  int g = 0; float wv = 0.f;
  if(pos < e1){ g = glist[pos]; wv = w[(size_t)pos*8 + h]; }
  while(pos < e1){
    int pos2 = pos + 4;
    int g2 = 0; float wv2 = 0.f;
    if(pos2 < e1){ g2 = glist[pos2]; wv2 = w[(size_t)pos2*8 + h]; }
    uint2 v = *(const uint2*)(V + (size_t)g*256 + ft*4);
    acc.x += wv * b2f(v.x & 0xffff);
    acc.y += wv * b2f(v.x >> 16);
    acc.z += wv * b2f(v.y & 0xffff);
    acc.w += wv * b2f(v.y >> 16);
    pos = pos2; g = g2; wv = wv2;
  }
  *(float4*)&part[grp][ft*4] = acc;
  __syncthreads();
  int f = t;
  float sum = part[0][f] + part[1][f] + part[2][f] + part[3][f];
  float out = sum * winv[(size_t)s*8 + (f>>5)] + attp[f];
  float mu  = block_sum256(out, red) * (1.f/256.f);
  float dd  = out - mu;
  float var = block_sum256(dd*dd, red) * (1.f/256.f);
  U[(size_t)s*256 + f] = f2b(dd * rsqrtf(var + 1e-5f) * g0[f] + b0[f]);
}

// ---------------- readout: chunked segment-sum with atomics ----------------
__global__ __launch_bounds__(256) void readout_acc(const unsigned short* __restrict__ X,
    const int* __restrict__ offsb, const int* __restrict__ nidx, float* __restrict__ ro){
  int b = blockIdx.x, chunk = blockIdx.y, t = threadIdx.x;
  int e0 = offsb[b], e1 = offsb[b+1];
  int len = e1 - e0;
  int per = (len + gridDim.y - 1) / gridDim.y;
  int s0 = e0 + chunk*per;
  int s1 = min(s0 + per, e1);
  if(s0 >= s1) return;
  float s = 0.f;
  for(int i=s0; i<s1; i++) s += b2f((unsigned int)X[(size_t)nidx[i]*256 + t]);
  atomicAdd(&ro[b*256 + t], s);
}

// ---------------- classifier ----------------
__global__ __launch_bounds__(128) void classifier_k(const float* __restrict__ ro,
    const int* __restrict__ offsb,
    const float* __restrict__ cW1, const float* __restrict__ cb1,
    const float* __restrict__ clng, const float* __restrict__ clnb,
    const float* __restrict__ cW2, const float* __restrict__ cb2, float* __restrict__ out){
  __shared__ float xs[256];
  __shared__ float hs[128];
  __shared__ float red[2];
  int b = blockIdx.x, j = threadIdx.x;
  int cnt = offsb[b+1] - offsb[b];
  float sc = 1.f / ((cnt > 0) ? (float)cnt : 1.f);
  xs[j] = ro[b*256 + j]*sc; xs[j+128] = ro[b*256 + j + 128]*sc;
  __syncthreads();
  float hv = cb1[j];
  for(int c=0; c<256; c++) hv += xs[c]*cW1[c*128 + j];
  float v = hv;
  #pragma unroll
  for(int mm=32; mm; mm>>=1) v += __shfl_xor(v, mm);
  if((j & 63) == 0) red[j>>6] = v;
  __syncthreads();
  float mu = (red[0] + red[1]) * (1.f/128.f);
  __syncthreads();
  float dd = hv - mu;
  v = dd*dd;
  #pragma unroll
  for(int mm=32; mm; mm>>=1) v += __shfl_xor(v, mm);
  if((j & 63) == 0) red[j>>6] = v;
  __syncthreads();
  float var = (red[0] + red[1]) * (1.f/128.f);
  float hn = fmaxf(dd * rsqrtf(var + 1e-5f) * clng[j] + clnb[j], 0.f);
  hs[j] = hn;
  __syncthreads();
  if(j < 10){
    float o = cb2[j];
    #pragma unroll
    for(int c=0; c<128; c++) o += hs[c]*cW2[c*10 + j];
    out[b*10 + j] = o;
  }
}

extern "C" void kernel_launch(void* const* d_in, const int* in_sizes, int n_in,
                              void* d_out, int out_size, void* d_ws, size_t ws_size,
                              hipStream_t stream){
  const float* X0   = (const float*)d_in[0];
  const int*   src  = (const int*)d_in[1];
  const int*   dst  = (const int*)d_in[2];
  const int*   batch= (const int*)d_in[3];
  const float* Wk   = (const float*)d_in[6];
  const float* bk   = (const float*)d_in[7];
  const float* Wv   = (const float*)d_in[8];
  const float* bv   = (const float*)d_in[9];
  const float* att  = (const float*)d_in[10];
  const float* ln0g = (const float*)d_in[11];
  const float* ln0b = (const float*)d_in[12];
  const float* ln1g = (const float*)d_in[13];
  const float* ln1b = (const float*)d_in[14];
  const float* W1   = (const float*)d_in[15];
  const float* b1   = (const float*)d_in[16];
  const float* W2   = (const float*)d_in[17];
  const float* b2   = (const float*)d_in[18];
  const float* cW1  = (const float*)d_in[19];
  const float* cb1  = (const float*)d_in[20];
  const float* clng = (const float*)d_in[21];
  const float* clnb = (const float*)d_in[22];
  const float* cW2  = (const float*)d_in[23];
  const float* cb2  = (const float*)d_in[24];

  const int N = in_sizes[0] / D;     // 100000
  const int E = in_sizes[1];         // 400000
  const int M = 20000, B = 64;
  const int nbb = (N + 255) / 256;   // batch-sort blocks

  char* p = (char*)d_ws;
  auto carve = [&](size_t bytes)->void*{
    void* r = (void*)p; p += (bytes + 255) & ~(size_t)255; return r;
  };
  unsigned short* Xb   = (unsigned short*)carve((size_t)N*D*2);
  unsigned short* bufA = (unsigned short*)carve((size_t)N*D*2);
  unsigned short* bufV = (unsigned short*)carve((size_t)N*D*2);
  unsigned short* WtAll= (unsigned short*)carve((size_t)3*4*65536*2);
  float* wE     = (float*)carve((size_t)E*8*4);
  float* winv   = (float*)carve((size_t)N*8*4);
  float* alphaB = (float*)carve((size_t)N*8*4);
  float* batt   = (float*)carve(4*NHEAD*4);
  int* offs_dst = (int*)carve((size_t)(M+1)*4);
  int* offs_src = (int*)carve((size_t)(N+1)*4);
  int* offs_b   = (int*)carve((size_t)(B+1)*4);
  int* sorted_dst = (int*)carve((size_t)E*4);
  int* sorted_src = (int*)carve((size_t)E*4);
  int* sorted_b   = (int*)carve((size_t)N*4);
  int* bsums    = (int*)carve(1024*4);
  int* gcnt     = (int*)carve((size_t)64*nbb*4);
  int* boffs    = (int*)carve(((size_t)64*nbb + 1)*4);
  char* z0 = p;                       // contiguous zero-init block
  unsigned short* wattb = (unsigned short*)carve((size_t)4*16*256*2);
  int* cnt_dst = (int*)carve((size_t)M*4);
  int* cnt_src = (int*)carve((size_t)N*4);
  int* fill_dst= (int*)carve((size_t)M*4);
  int* fill_src= (int*)carve((size_t)N*4);
  float* ro    = (float*)carve((size_t)B*D*4);
  size_t zbytes = (size_t)(p - z0);
  hipMemsetAsync(z0, 0, zbytes, stream);

  // conversions
  conv_x_k<<<(N*D/8+255)/256,256,0,stream>>>(X0, Xb, N*D/8);
  dim3 gw(16, 12);
  conv_wt_k<<<gw,256,0,stream>>>(Wv, W1, W2, WtAll);
  prep_watt_k<<<(4*NHEAD*D+255)/256,256,0,stream>>>(Wk, bk, att, wattb, batt);

  // edge CSRs (atomic fill; low contention)
  hist_edges_k<<<(E+255)/256,256,0,stream>>>(src, dst, cnt_src, cnt_dst, E);
  auto scan = [&](const int* cnt, int* offs, int n){
    int nb = (n+255)/256;
    scan_pass1<<<nb,256,0,stream>>>(cnt, offs, bsums, n);
    scan_pass2<<<1,1024,0,stream>>>(bsums, nb);
    scan_pass3<<<(n+255)/256,256,0,stream>>>(offs, bsums, n);
  };
  scan(cnt_dst, offs_dst, M);
  fill_csr_k<<<(E+255)/256,256,0,stream>>>(dst, src, offs_dst, fill_dst, sorted_dst, E);
  scan(cnt_src, offs_src, N);
  fill_csr_k<<<(E+255)/256,256,0,stream>>>(src, dst, offs_src, fill_src, sorted_src, E);

  // batch CSR via counting sort (no hot global atomics)
  bhist_k<<<nbb,256,0,stream>>>(batch, gcnt, N, nbb);
  scan(gcnt, boffs, 64*nbb);
  boffs_fin<<<1,128,0,stream>>>(boffs, offs_b, nbb, N);
  bfill_k<<<nbb,256,0,stream>>>(batch, boffs, sorted_b, N, nbb);

  const unsigned short* xin = Xb;
  for(int pi=0; pi<4; pi++){
    int n_rows = (pi & 1) ? M : N;
    int nseg   = (pi & 1) ? N : M;
    const int* offs = (pi & 1) ? offs_src : offs_dst;
    const int* gl   = (pi & 1) ? sorted_src : sorted_dst;
    const unsigned short* WvT = WtAll + (size_t)0*262144 + (size_t)pi*65536;
    const unsigned short* W1T = WtAll + (size_t)1*262144 + (size_t)pi*65536;
    const unsigned short* W2T = WtAll + (size_t)2*262144 + (size_t)pi*65536;

    gemm_valpha<<<(n_rows+63)/64,256,0,stream>>>(xin, WvT, bv + pi*D,
        wattb + (size_t)pi*16*256, batt + pi*NHEAD, bufV, alphaB, n_rows);
    pma_weights<<<nseg,256,0,stream>>>(alphaB, offs, gl, wE, winv, nseg);
    pma_pool2<<<nseg,256,0,stream>>>(bufV, wE, winv, offs, gl,
        att + pi*D, ln0g + pi*D, ln0b + pi*D, bufA, nseg);
    rff_fused<<<(nseg+63)/64,256,0,stream>>>(bufA, W1T, b1 + pi*D, W2T, b2 + pi*D,
        ln1g + pi*D, ln1b + pi*D, nseg);
    xin = bufA;
  }

  dim3 gr(B, 16);
  readout_acc<<<gr,256,0,stream>>>(bufA, offs_b, sorted_b, ro);
  classifier_k<<<B,128,0,stream>>>(ro, offs_b, cW1, cb1, clng, clnb, cW2, cb2, (float*)d_out);
}

// Round 6
// 805.415 us; speedup vs baseline: 4.2577x; 1.4110x over previous
//
#include <hip/hip_runtime.h>
#include <stdint.h>
#include <stddef.h>

#define D 256
#define NHEAD 8

typedef short bf16x8 __attribute__((ext_vector_type(8)));
typedef float f32x4  __attribute__((ext_vector_type(4)));
typedef unsigned int u32x4 __attribute__((ext_vector_type(4)));

__device__ __forceinline__ unsigned short f2b(float f){
  uint32_t u = __float_as_uint(f);
  u += 0x7FFF + ((u >> 16) & 1);
  return (unsigned short)(u >> 16);
}
__device__ __forceinline__ float b2f(unsigned int b){
  return __uint_as_float(b << 16);
}
__device__ __forceinline__ void gload_lds16(const void* g, void* l){
  __builtin_amdgcn_global_load_lds((const __attribute__((address_space(1))) void*)g,
                                   (__attribute__((address_space(3))) void*)l, 16, 0, 0);
}

// ---------------- CSR build (edges: atomic fill; contention <= 20-way, fine) ----------------
__global__ void hist_edges_k(const int* __restrict__ src, const int* __restrict__ dst,
                             int* cnt_src, int* cnt_dst, int E){
  int e = blockIdx.x*blockDim.x + threadIdx.x;
  if(e < E){ atomicAdd(&cnt_dst[dst[e]],1); atomicAdd(&cnt_src[src[e]],1); }
}
__global__ void scan_pass1(const int* __restrict__ cnt, int* offs, int* bsums, int n){
  __shared__ int tmp[256];
  int g = blockIdx.x, t = threadIdx.x, i = g*256 + t;
  int v = (i < n) ? cnt[i] : 0;
  tmp[t] = v; __syncthreads();
  for(int off=1; off<256; off<<=1){
    int a = (t>=off) ? tmp[t-off] : 0; __syncthreads();
    tmp[t] += a; __syncthreads();
  }
  if(i < n) offs[i+1] = tmp[t];
  if(t == 255) bsums[g] = tmp[255];
}
__global__ void scan_pass2(int* bsums, int nb){
  __shared__ int tmp[1024];
  int t = threadIdx.x;
  int v = (t < nb) ? bsums[t] : 0;
  tmp[t] = v; __syncthreads();
  for(int off=1; off<1024; off<<=1){
    int a = (t>=off) ? tmp[t-off] : 0; __syncthreads();
    tmp[t] += a; __syncthreads();
  }
  if(t < nb) bsums[t] = tmp[t] - v;   // exclusive
}
__global__ void scan_pass3(int* offs, const int* bsums, int n){
  int i = blockIdx.x*blockDim.x + threadIdx.x;
  if(i == 0) offs[0] = 0;
  if(i < n) offs[i+1] += bsums[i>>8];
}
__global__ void fill_csr_k(const int* __restrict__ seg, const int* __restrict__ other,
                           const int* __restrict__ offs, int* fill, int* sorted, int E){
  int e = blockIdx.x*blockDim.x + threadIdx.x;
  if(e < E){
    int s = seg[e];
    int p = offs[s] + atomicAdd(&fill[s],1);
    sorted[p] = other[e];
  }
}

// ---------------- batch CSR via counting sort ----------------
__global__ __launch_bounds__(256) void bhist_k(const int* __restrict__ batch, int* __restrict__ gcnt,
                                               int N, int nb){
  __shared__ int h[64];
  int t = threadIdx.x, blk = blockIdx.x;
  if(t < 64) h[t] = 0;
  __syncthreads();
  int i = blk*256 + t;
  if(i < N) atomicAdd(&h[batch[i]], 1);
  __syncthreads();
  if(t < 64) gcnt[t*nb + blk] = h[t];
}
__global__ void boffs_fin(const int* __restrict__ boffs, int* __restrict__ offs_b, int nb, int N){
  int t = threadIdx.x;
  if(t < 64) offs_b[t] = boffs[t*nb];
  if(t == 64) offs_b[64] = N;
}
__global__ __launch_bounds__(256) void bfill_k(const int* __restrict__ batch,
    const int* __restrict__ boffs, int* __restrict__ sorted_b, int N, int nb){
  __shared__ int base[64];
  __shared__ int cnt[64];
  int t = threadIdx.x, blk = blockIdx.x;
  if(t < 64){ base[t] = boffs[t*nb + blk]; cnt[t] = 0; }
  __syncthreads();
  int i = blk*256 + t;
  if(i < N){
    int b = batch[i];
    int r = atomicAdd(&cnt[b], 1);
    sorted_b[base[b] + r] = i;
  }
}

// ---------------- conversions ----------------
__global__ void conv_x_k(const float* __restrict__ X, unsigned short* __restrict__ Xb, int total8){
  int i = blockIdx.x*blockDim.x + threadIdx.x;
  if(i >= total8) return;
  float4 a = ((const float4*)X)[2*i], b = ((const float4*)X)[2*i+1];
  union { unsigned short u[8]; u32x4 v; } o;
  o.u[0]=f2b(a.x); o.u[1]=f2b(a.y); o.u[2]=f2b(a.z); o.u[3]=f2b(a.w);
  o.u[4]=f2b(b.x); o.u[5]=f2b(b.y); o.u[6]=f2b(b.z); o.u[7]=f2b(b.w);
  ((u32x4*)Xb)[i] = o.v;
}

// Wt[s][p][n][k] = W[p][k][n] bf16 via LDS tile transpose
__global__ __launch_bounds__(256) void conv_wt_k(const float* __restrict__ Wv,
    const float* __restrict__ W1, const float* __restrict__ W2, unsigned short* __restrict__ Wt){
  __shared__ unsigned short lds[64][65];
  int sp = blockIdx.y; int s = sp >> 2, p = sp & 3;
  const float* W = (s==0?Wv:(s==1?W1:W2)) + (size_t)p*65536;
  int k0 = (blockIdx.x & 3)*64, n0 = (blockIdx.x >> 2)*64;
  for(int r=0;r<16;r++){
    int idx = r*256 + threadIdx.x;
    int row = idx >> 6, col = idx & 63;
    lds[col][row] = f2b(W[(size_t)(k0+row)*256 + n0+col]);
  }
  __syncthreads();
  unsigned short* out = Wt + (size_t)s*262144 + (size_t)p*65536;
  for(int r=0;r<16;r++){
    int idx = r*256 + threadIdx.x;
    int orow = idx >> 6, ocol = idx & 63;
    out[(size_t)(n0+orow)*256 + k0+ocol] = lds[orow][ocol];
  }
}

// ---------------- params prep ----------------
__global__ void prep_watt_k(const float* __restrict__ Wk, const float* __restrict__ bk,
                            const float* __restrict__ att, unsigned short* __restrict__ wattb,
                            float* __restrict__ batt){
  int tid = blockIdx.x*blockDim.x + threadIdx.x;
  if(tid < 4*NHEAD*D){
    int c = tid & (D-1); int h = (tid>>8) & 7; int p = tid >> 11;
    const float* Wp = Wk + (size_t)p*D*D + (size_t)c*D + h*32;
    const float* ap = att + (size_t)p*D + h*32;
    float s = 0.f;
    #pragma unroll
    for(int d=0; d<32; d++) s += Wp[d]*ap[d];
    wattb[((size_t)(p*16 + h))*256 + c] = f2b(s);
  }
  if(tid < 4*NHEAD){
    int h = tid & 7, p = tid >> 3;
    const float* bp = bk + (size_t)p*D + h*32;
    const float* ap = att + (size_t)p*D + h*32;
    float s = 0.f;
    #pragma unroll
    for(int d=0; d<32; d++) s += bp[d]*ap[d];
    batt[tid] = s;
  }
}

// ---------------- V-GEMM + fused alpha ----------------
__global__ __launch_bounds__(256) void gemm_valpha(const unsigned short* __restrict__ A,
    const unsigned short* __restrict__ Wt, const float* __restrict__ bias,
    const unsigned short* __restrict__ wattb, const float* __restrict__ batt8,
    unsigned short* __restrict__ C, float* __restrict__ alpha, int n){
  __shared__ unsigned short As[64*256];
  const int tid = threadIdx.x;
  const int row0 = blockIdx.x*64;
  #pragma unroll
  for(int i=0;i<8;i++){
    int a = i*4096 + tid*16;
    int row = a >> 9;
    int within = a & 511;
    int srcw = within ^ ((row & 7) << 4);
    int grow = row0 + row; grow = (grow < n) ? grow : (n-1);
    const void* gp = (const void*)((const char*)A + (size_t)grow*512 + srcw);
    void* lp = (void*)((char*)As + i*4096 + (tid & 192)*16);
    gload_lds16(gp, lp);
  }
  __syncthreads();
  const int wc = tid >> 6;
  const int l  = tid & 63;
  const int lr = l & 15, lg = l >> 4;
  f32x4 acc[4][4] = {};
  f32x4 accw = {0.f,0.f,0.f,0.f};
  const char* Asb = (const char*)As;
  const int roww = wc*16 + lr;
  #pragma unroll
  for(int k0=0; k0<256; k0+=32){
    bf16x8 af[4], bf_[4];
    #pragma unroll
    for(int mi=0;mi<4;mi++){
      int row = mi*16 + lr;
      af[mi] = *(const bf16x8*)(Asb + row*512 + ((k0*2 + lg*16) ^ ((row & 7) << 4)));
    }
    #pragma unroll
    for(int ni=0;ni<4;ni++){
      int col = wc*64 + ni*16 + lr;
      bf_[ni] = *(const bf16x8*)(Wt + (size_t)col*256 + k0 + lg*8);
    }
    bf16x8 afw = *(const bf16x8*)(Asb + roww*512 + ((k0*2 + lg*16) ^ ((roww & 7) << 4)));
    bf16x8 bfw = *(const bf16x8*)((const char*)wattb + lr*512 + k0*2 + lg*16);
    #pragma unroll
    for(int mi=0;mi<4;mi++)
      #pragma unroll
      for(int ni=0;ni<4;ni++)
        acc[mi][ni] = __builtin_amdgcn_mfma_f32_16x16x32_bf16(af[mi], bf_[ni], acc[mi][ni], 0,0,0);
    accw = __builtin_amdgcn_mfma_f32_16x16x32_bf16(afw, bfw, accw, 0,0,0);
  }
  // alpha epilogue
  #pragma unroll
  for(int r4=0;r4<4;r4++){
    int grow = row0 + wc*16 + lg*4 + r4;
    if(lr < 8 && grow < n) alpha[(size_t)grow*8 + lr] = accw[r4] + batt8[lr];
  }
  // C epilogue via LDS transpose -> full-line NT stores
  __syncthreads();
  #pragma unroll
  for(int mi=0;mi<4;mi++)
    #pragma unroll
    for(int ni=0;ni<4;ni++){
      int col = wc*64 + ni*16 + lr;
      #pragma unroll
      for(int r4=0;r4<4;r4++){
        int row = mi*16 + lg*4 + r4;
        *(unsigned short*)((char*)As + row*512 + col*2) = f2b(acc[mi][ni][r4] + bias[col]);
      }
    }
  __syncthreads();
  #pragma unroll
  for(int i=0;i<8;i++){
    int idx = i*4096 + tid*16;
    int row = idx >> 9, wb = idx & 511;
    int grow = row0 + row;
    if(grow < n){
      u32x4 val = *(const u32x4*)((const char*)As + idx);
      __builtin_nontemporal_store(val, (u32x4*)((char*)C + (size_t)grow*512 + wb));
    }
  }
}

// ---------------- fused rFF: U = relu(LN1(U + relu(relu(U@W1+b1)@W2+b2))), in-place ----------------
__global__ __launch_bounds__(256) void rff_fused(unsigned short* __restrict__ U,
    const unsigned short* __restrict__ W1t, const float* __restrict__ b1p,
    const unsigned short* __restrict__ W2t, const float* __restrict__ b2p,
    const float* __restrict__ g1, const float* __restrict__ b1n, int n){
  __shared__ unsigned short As[64*256];
  __shared__ unsigned short Hs[64*256];
  __shared__ float rsum[64][4];
  __shared__ float muv[64];
  __shared__ float rsv[64];
  const int tid = threadIdx.x;
  const int row0 = blockIdx.x*64;
  #pragma unroll
  for(int i=0;i<8;i++){
    int a = i*4096 + tid*16;
    int row = a >> 9;
    int within = a & 511;
    int srcw = within ^ ((row & 7) << 4);
    int grow = row0 + row; grow = (grow < n) ? grow : (n-1);
    const void* gp = (const void*)((const char*)U + (size_t)grow*512 + srcw);
    void* lp = (void*)((char*)As + i*4096 + (tid & 192)*16);
    gload_lds16(gp, lp);
  }
  __syncthreads();
  const int wc = tid >> 6;
  const int l  = tid & 63;
  const int lr = l & 15, lg = l >> 4;
  const char* Asb = (const char*)As;
  char* Hsb = (char*)Hs;
  float bias1[4], bias2[4], gg[4], bb[4];
  #pragma unroll
  for(int ni=0;ni<4;ni++){
    int col = wc*64 + ni*16 + lr;
    bias1[ni] = b1p[col]; bias2[ni] = b2p[col]; gg[ni] = g1[col]; bb[ni] = b1n[col];
  }
  const f32x4 zz = {0.f,0.f,0.f,0.f};
  f32x4 acc[4][4] = {};
  // GEMM1: H = relu(A@W1 + b1)
  #pragma unroll
  for(int k0=0; k0<256; k0+=32){
    bf16x8 af[4], bf_[4];
    #pragma unroll
    for(int mi=0;mi<4;mi++){
      int row = mi*16 + lr;
      af[mi] = *(const bf16x8*)(Asb + row*512 + ((k0*2 + lg*16) ^ ((row & 7) << 4)));
    }
    #pragma unroll
    for(int ni=0;ni<4;ni++){
      int col = wc*64 + ni*16 + lr;
      bf_[ni] = *(const bf16x8*)(W1t + (size_t)col*256 + k0 + lg*8);
    }
    #pragma unroll
    for(int mi=0;mi<4;mi++)
      #pragma unroll
      for(int ni=0;ni<4;ni++)
        acc[mi][ni] = __builtin_amdgcn_mfma_f32_16x16x32_bf16(af[mi], bf_[ni], acc[mi][ni], 0,0,0);
  }
  #pragma unroll
  for(int mi=0;mi<4;mi++)
    #pragma unroll
    for(int ni=0;ni<4;ni++){
      int col = wc*64 + ni*16 + lr;
      #pragma unroll
      for(int r4=0;r4<4;r4++){
        int row = mi*16 + lg*4 + r4;
        *(unsigned short*)(Hsb + row*512 + ((col*2) ^ ((row & 7) << 4))) =
            f2b(fmaxf(acc[mi][ni][r4] + bias1[ni], 0.f));
      }
    }
  __syncthreads();
  // GEMM2: R = H@W2 + b2
  #pragma unroll
  for(int mi=0;mi<4;mi++)
    #pragma unroll
    for(int ni=0;ni<4;ni++)
      acc[mi][ni] = zz;
  #pragma unroll
  for(int k0=0; k0<256; k0+=32){
    bf16x8 af[4], bf_[4];
    #pragma unroll
    for(int mi=0;mi<4;mi++){
      int row = mi*16 + lr;
      af[mi] = *(const bf16x8*)(Hsb + row*512 + ((k0*2 + lg*16) ^ ((row & 7) << 4)));
    }
    #pragma unroll
    for(int ni=0;ni<4;ni++){
      int col = wc*64 + ni*16 + lr;
      bf_[ni] = *(const bf16x8*)(W2t + (size_t)col*256 + k0 + lg*8);
    }
    #pragma unroll
    for(int mi=0;mi<4;mi++)
      #pragma unroll
      for(int ni=0;ni<4;ni++)
        acc[mi][ni] = __builtin_amdgcn_mfma_f32_16x16x32_bf16(af[mi], bf_[ni], acc[mi][ni], 0,0,0);
  }
  // v = U + relu(R)
  f32x4 v[4][4];
  #pragma unroll
  for(int mi=0;mi<4;mi++)
    #pragma unroll
    for(int ni=0;ni<4;ni++){
      int col = wc*64 + ni*16 + lr;
      #pragma unroll
      for(int r4=0;r4<4;r4++){
        int row = mi*16 + lg*4 + r4;
        unsigned short u = *(const unsigned short*)(Asb + row*512 + ((col*2) ^ ((row & 7) << 4)));
        v[mi][ni][r4] = b2f(u) + fmaxf(acc[mi][ni][r4] + bias2[ni], 0.f);
      }
    }
  // row means
  f32x4 rp[4];
  #pragma unroll
  for(int mi=0;mi<4;mi++){
    rp[mi] = v[mi][0] + v[mi][1] + v[mi][2] + v[mi][3];
    #pragma unroll
    for(int c=0;c<4;c++){
      float x = rp[mi][c];
      x += __shfl_xor(x, 1); x += __shfl_xor(x, 2);
      x += __shfl_xor(x, 4); x += __shfl_xor(x, 8);
      rp[mi][c] = x;
    }
  }
  if(lr == 0){
    #pragma unroll
    for(int mi=0;mi<4;mi++)
      #pragma unroll
      for(int r4=0;r4<4;r4++)
        rsum[mi*16 + lg*4 + r4][wc] = rp[mi][r4];
  }
  __syncthreads();
  if(tid < 64) muv[tid] = (rsum[tid][0]+rsum[tid][1]+rsum[tid][2]+rsum[tid][3]) * (1.f/256.f);
  __syncthreads();
  #pragma unroll
  for(int mi=0;mi<4;mi++)
    #pragma unroll
    for(int ni=0;ni<4;ni++)
      #pragma unroll
      for(int r4=0;r4<4;r4++){
        int row = mi*16 + lg*4 + r4;
        v[mi][ni][r4] -= muv[row];
      }
  #pragma unroll
  for(int mi=0;mi<4;mi++){
    rp[mi] = v[mi][0]*v[mi][0] + v[mi][1]*v[mi][1] + v[mi][2]*v[mi][2] + v[mi][3]*v[mi][3];
    #pragma unroll
    for(int c=0;c<4;c++){
      float x = rp[mi][c];
      x += __shfl_xor(x, 1); x += __shfl_xor(x, 2);
      x += __shfl_xor(x, 4); x += __shfl_xor(x, 8);
      rp[mi][c] = x;
    }
  }
  if(lr == 0){
    #pragma unroll
    for(int mi=0;mi<4;mi++)
      #pragma unroll
      for(int r4=0;r4<4;r4++)
        rsum[mi*16 + lg*4 + r4][wc] = rp[mi][r4];
  }
  __syncthreads();
  if(tid < 64) rsv[tid] = rsqrtf((rsum[tid][0]+rsum[tid][1]+rsum[tid][2]+rsum[tid][3]) * (1.f/256.f) + 1e-5f);
  __syncthreads();
  // stage y into Hs (linear layout), then full-line NT stores
  #pragma unroll
  for(int mi=0;mi<4;mi++)
    #pragma unroll
    for(int ni=0;ni<4;ni++){
      int col = wc*64 + ni*16 + lr;
      #pragma unroll
      for(int r4=0;r4<4;r4++){
        int row = mi*16 + lg*4 + r4;
        *(unsigned short*)(Hsb + row*512 + col*2) =
            f2b(fmaxf(v[mi][ni][r4]*rsv[row]*gg[ni] + bb[ni], 0.f));
      }
    }
  __syncthreads();
  #pragma unroll
  for(int i=0;i<8;i++){
    int idx = i*4096 + tid*16;
    int row = idx >> 9, wb = idx & 511;
    int grow = row0 + row;
    if(grow < n){
      u32x4 val = *(const u32x4*)(Hsb + idx);
      __builtin_nontemporal_store(val, (u32x4*)((char*)U + (size_t)grow*512 + wb));
    }
  }
}

// ---------------- fused pool: softmax weights inline + weighted V sum + residual + LN0 ----------------
// one wave per segment; halves process alternate edges; lane j of half owns feats 8j..8j+7
__global__ __launch_bounds__(256) void pool_ln0(const unsigned short* __restrict__ V,
    const float* __restrict__ alpha,
    const int* __restrict__ offs, const int* __restrict__ glist,
    const float* __restrict__ attp, const float* __restrict__ g0, const float* __restrict__ b0,
    unsigned short* __restrict__ U, int nseg){
  int s = blockIdx.x*4 + (threadIdx.x >> 6);
  if(s >= nseg) return;
  const int l = threadIdx.x & 63;
  const int half = l >> 5, j = l & 31, h = j >> 2;
  const int e0 = offs[s], e1 = offs[s+1];
  // pass 1: per-head max of leaky(alpha)
  float m = -3.0e38f;
  for(int pos = e0 + half; pos < e1; pos += 2){
    float a = alpha[(size_t)glist[pos]*8 + h];
    a = (a > 0.f) ? a : 0.2f*a;
    m = fmaxf(m, a);
  }
  m = fmaxf(m, __shfl_xor(m, 32));
  // pass 2: exp-weighted V accumulate
  float acc[8] = {0.f,0.f,0.f,0.f,0.f,0.f,0.f,0.f};
  float sw = 0.f;
  for(int pos = e0 + half; pos < e1; pos += 2){
    int g = glist[pos];
    float a = alpha[(size_t)g*8 + h];
    a = (a > 0.f) ? a : 0.2f*a;
    float w = __expf(a - m);
    sw += w;
    u32x4 v = *(const u32x4*)(V + (size_t)g*256 + j*8);
    acc[0] += w*b2f(v.x & 0xffff); acc[1] += w*b2f(v.x >> 16);
    acc[2] += w*b2f(v.y & 0xffff); acc[3] += w*b2f(v.y >> 16);
    acc[4] += w*b2f(v.z & 0xffff); acc[5] += w*b2f(v.z >> 16);
    acc[6] += w*b2f(v.w & 0xffff); acc[7] += w*b2f(v.w >> 16);
  }
  sw += __shfl_xor(sw, 32);
  #pragma unroll
  for(int k=0;k<8;k++) acc[k] += __shfl_xor(acc[k], 32);
  float inv = 1.f/((sw > 0.f) ? sw : 1.f);
  float4 ap0 = *(const float4*)(attp + j*8);
  float4 ap1 = *(const float4*)(attp + j*8 + 4);
  float out[8];
  out[0]=acc[0]*inv+ap0.x; out[1]=acc[1]*inv+ap0.y; out[2]=acc[2]*inv+ap0.z; out[3]=acc[3]*inv+ap0.w;
  out[4]=acc[4]*inv+ap1.x; out[5]=acc[5]*inv+ap1.y; out[6]=acc[6]*inv+ap1.z; out[7]=acc[7]*inv+ap1.w;
  float loc = out[0]+out[1]+out[2]+out[3]+out[4]+out[5]+out[6]+out[7];
  loc += __shfl_xor(loc,1); loc += __shfl_xor(loc,2); loc += __shfl_xor(loc,4);
  loc += __shfl_xor(loc,8); loc += __shfl_xor(loc,16);
  float mu = loc * (1.f/256.f);
  float sq = 0.f;
  #pragma unroll
  for(int k=0;k<8;k++){ out[k] -= mu; sq += out[k]*out[k]; }
  sq += __shfl_xor(sq,1); sq += __shfl_xor(sq,2); sq += __shfl_xor(sq,4);
  sq += __shfl_xor(sq,8); sq += __shfl_xor(sq,16);
  float rs = rsqrtf(sq * (1.f/256.f) + 1e-5f);
  if(half == 0){
    float4 gg0 = *(const float4*)(g0 + j*8);
    float4 gg1 = *(const float4*)(g0 + j*8 + 4);
    float4 bb0 = *(const float4*)(b0 + j*8);
    float4 bb1 = *(const float4*)(b0 + j*8 + 4);
    unsigned short y0 = f2b(out[0]*rs*gg0.x + bb0.x);
    unsigned short y1 = f2b(out[1]*rs*gg0.y + bb0.y);
    unsigned short y2 = f2b(out[2]*rs*gg0.z + bb0.z);
    unsigned short y3 = f2b(out[3]*rs*gg0.w + bb0.w);
    unsigned short y4 = f2b(out[4]*rs*gg1.x + bb1.x);
    unsigned short y5 = f2b(out[5]*rs*gg1.y + bb1.y);
    unsigned short y6 = f2b(out[6]*rs*gg1.z + bb1.z);
    unsigned short y7 = f2b(out[7]*rs*gg1.w + bb1.w);
    u32x4 o;
    o.x = (uint32_t)y0 | ((uint32_t)y1 << 16);
    o.y = (uint32_t)y2 | ((uint32_t)y3 << 16);
    o.z = (uint32_t)y4 | ((uint32_t)y5 << 16);
    o.w = (uint32_t)y6 | ((uint32_t)y7 << 16);
    __builtin_nontemporal_store(o, (u32x4*)(U + (size_t)s*256 + j*8));
  }
}

// ---------------- readout: chunked segment-sum with atomics ----------------
__global__ __launch_bounds__(256) void readout_acc(const unsigned short* __restrict__ X,
    const int* __restrict__ offsb, const int* __restrict__ nidx, float* __restrict__ ro){
  int b = blockIdx.x, chunk = blockIdx.y, t = threadIdx.x;
  int e0 = offsb[b], e1 = offsb[b+1];
  int len = e1 - e0;
  int per = (len + gridDim.y - 1) / gridDim.y;
  int s0 = e0 + chunk*per;
  int s1 = min(s0 + per, e1);
  if(s0 >= s1) return;
  float s = 0.f;
  for(int i=s0; i<s1; i++) s += b2f((unsigned int)X[(size_t)nidx[i]*256 + t]);
  atomicAdd(&ro[b*256 + t], s);
}

// ---------------- classifier ----------------
__global__ __launch_bounds__(128) void classifier_k(const float* __restrict__ ro,
    const int* __restrict__ offsb,
    const float* __restrict__ cW1, const float* __restrict__ cb1,
    const float* __restrict__ clng, const float* __restrict__ clnb,
    const float* __restrict__ cW2, const float* __restrict__ cb2, float* __restrict__ out){
  __shared__ float xs[256];
  __shared__ float hs[128];
  __shared__ float red[2];
  int b = blockIdx.x, j = threadIdx.x;
  int cnt = offsb[b+1] - offsb[b];
  float sc = 1.f / ((cnt > 0) ? (float)cnt : 1.f);
  xs[j] = ro[b*256 + j]*sc; xs[j+128] = ro[b*256 + j + 128]*sc;
  __syncthreads();
  float hv = cb1[j];
  for(int c=0; c<256; c++) hv += xs[c]*cW1[c*128 + j];
  float v = hv;
  #pragma unroll
  for(int mm=32; mm; mm>>=1) v += __shfl_xor(v, mm);
  if((j & 63) == 0) red[j>>6] = v;
  __syncthreads();
  float mu = (red[0] + red[1]) * (1.f/128.f);
  __syncthreads();
  float dd = hv - mu;
  v = dd*dd;
  #pragma unroll
  for(int mm=32; mm; mm>>=1) v += __shfl_xor(v, mm);
  if((j & 63) == 0) red[j>>6] = v;
  __syncthreads();
  float var = (red[0] + red[1]) * (1.f/128.f);
  float hn = fmaxf(dd * rsqrtf(var + 1e-5f) * clng[j] + clnb[j], 0.f);
  hs[j] = hn;
  __syncthreads();
  if(j < 10){
    float o = cb2[j];
    #pragma unroll
    for(int c=0; c<128; c++) o += hs[c]*cW2[c*10 + j];
    out[b*10 + j] = o;
  }
}

extern "C" void kernel_launch(void* const* d_in, const int* in_sizes, int n_in,
                              void* d_out, int out_size, void* d_ws, size_t ws_size,
                              hipStream_t stream){
  const float* X0   = (const float*)d_in[0];
  const int*   src  = (const int*)d_in[1];
  const int*   dst  = (const int*)d_in[2];
  const int*   batch= (const int*)d_in[3];
  const float* Wk   = (const float*)d_in[6];
  const float* bk   = (const float*)d_in[7];
  const float* Wv   = (const float*)d_in[8];
  const float* bv   = (const float*)d_in[9];
  const float* att  = (const float*)d_in[10];
  const float* ln0g = (const float*)d_in[11];
  const float* ln0b = (const float*)d_in[12];
  const float* ln1g = (const float*)d_in[13];
  const float* ln1b = (const float*)d_in[14];
  const float* W1   = (const float*)d_in[15];
  const float* b1   = (const float*)d_in[16];
  const float* W2   = (const float*)d_in[17];
  const float* b2   = (const float*)d_in[18];
  const float* cW1  = (const float*)d_in[19];
  const float* cb1  = (const float*)d_in[20];
  const float* clng = (const float*)d_in[21];
  const float* clnb = (const float*)d_in[22];
  const float* cW2  = (const float*)d_in[23];
  const float* cb2  = (const float*)d_in[24];

  const int N = in_sizes[0] / D;     // 100000
  const int E = in_sizes[1];         // 400000
  const int M = 20000, B = 64;
  const int nbb = (N + 255) / 256;

  char* p = (char*)d_ws;
  auto carve = [&](size_t bytes)->void*{
    void* r = (void*)p; p += (bytes + 255) & ~(size_t)255; return r;
  };
  unsigned short* Xb   = (unsigned short*)carve((size_t)N*D*2);
  unsigned short* bufA = (unsigned short*)carve((size_t)N*D*2);
  unsigned short* bufV = (unsigned short*)carve((size_t)N*D*2);
  unsigned short* WtAll= (unsigned short*)carve((size_t)3*4*65536*2);
  float* alphaB = (float*)carve((size_t)N*8*4);
  float* batt   = (float*)carve(4*NHEAD*4);
  int* offs_dst = (int*)carve((size_t)(M+1)*4);
  int* offs_src = (int*)carve((size_t)(N+1)*4);
  int* offs_b   = (int*)carve((size_t)(B+1)*4);
  int* sorted_dst = (int*)carve((size_t)E*4);
  int* sorted_src = (int*)carve((size_t)E*4);
  int* sorted_b   = (int*)carve((size_t)N*4);
  int* bsums    = (int*)carve(1024*4);
  int* gcnt     = (int*)carve((size_t)64*nbb*4);
  int* boffs    = (int*)carve(((size_t)64*nbb + 1)*4);
  char* z0 = p;                       // contiguous zero-init block
  unsigned short* wattb = (unsigned short*)carve((size_t)4*16*256*2);
  int* cnt_dst = (int*)carve((size_t)M*4);
  int* cnt_src = (int*)carve((size_t)N*4);
  int* fill_dst= (int*)carve((size_t)M*4);
  int* fill_src= (int*)carve((size_t)N*4);
  float* ro    = (float*)carve((size_t)B*D*4);
  size_t zbytes = (size_t)(p - z0);
  hipMemsetAsync(z0, 0, zbytes, stream);

  // conversions
  conv_x_k<<<(N*D/8+255)/256,256,0,stream>>>(X0, Xb, N*D/8);
  dim3 gw(16, 12);
  conv_wt_k<<<gw,256,0,stream>>>(Wv, W1, W2, WtAll);
  prep_watt_k<<<(4*NHEAD*D+255)/256,256,0,stream>>>(Wk, bk, att, wattb, batt);

  // edge CSRs
  hist_edges_k<<<(E+255)/256,256,0,stream>>>(src, dst, cnt_src, cnt_dst, E);
  auto scan = [&](const int* cnt, int* offs, int n){
    int nb = (n+255)/256;
    scan_pass1<<<nb,256,0,stream>>>(cnt, offs, bsums, n);
    scan_pass2<<<1,1024,0,stream>>>(bsums, nb);
    scan_pass3<<<(n+255)/256,256,0,stream>>>(offs, bsums, n);
  };
  scan(cnt_dst, offs_dst, M);
  fill_csr_k<<<(E+255)/256,256,0,stream>>>(dst, src, offs_dst, fill_dst, sorted_dst, E);
  scan(cnt_src, offs_src, N);
  fill_csr_k<<<(E+255)/256,256,0,stream>>>(src, dst, offs_src, fill_src, sorted_src, E);

  // batch CSR via counting sort
  bhist_k<<<nbb,256,0,stream>>>(batch, gcnt, N, nbb);
  scan(gcnt, boffs, 64*nbb);
  boffs_fin<<<1,128,0,stream>>>(boffs, offs_b, nbb, N);
  bfill_k<<<nbb,256,0,stream>>>(batch, boffs, sorted_b, N, nbb);

  const unsigned short* xin = Xb;
  for(int pi=0; pi<4; pi++){
    int n_rows = (pi & 1) ? M : N;
    int nseg   = (pi & 1) ? N : M;
    const int* offs = (pi & 1) ? offs_src : offs_dst;
    const int* gl   = (pi & 1) ? sorted_src : sorted_dst;
    const unsigned short* WvT = WtAll + (size_t)0*262144 + (size_t)pi*65536;
    const unsigned short* W1T = WtAll + (size_t)1*262144 + (size_t)pi*65536;
    const unsigned short* W2T = WtAll + (size_t)2*262144 + (size_t)pi*65536;

    gemm_valpha<<<(n_rows+63)/64,256,0,stream>>>(xin, WvT, bv + pi*D,
        wattb + (size_t)pi*16*256, batt + pi*NHEAD, bufV, alphaB, n_rows);
    pool_ln0<<<(nseg+3)/4,256,0,stream>>>(bufV, alphaB, offs, gl,
        att + pi*D, ln0g + pi*D, ln0b + pi*D, bufA, nseg);
    rff_fused<<<(nseg+63)/64,256,0,stream>>>(bufA, W1T, b1 + pi*D, W2T, b2 + pi*D,
        ln1g + pi*D, ln1b + pi*D, nseg);
    xin = bufA;
  }

  dim3 gr(B, 16);
  readout_acc<<<gr,256,0,stream>>>(bufA, offs_b, sorted_b, ro);
  classifier_k<<<B,128,0,stream>>>(ro, offs_b, cW1, cb1, clng, clnb, cW2, cb2, (float*)d_out);
}